// Round 1
// baseline (2479.679 us; speedup 1.0000x reference)
//
#include <hip/hip_runtime.h>
#include <hip/hip_bf16.h>

#define N_NODES 50000
#define N_EDGES 800000
#define DIM 128
#define NLAYER 3
#define NEG 0.2f

// ---------------- utility ----------------
__global__ __launch_bounds__(256) void zero_kernel(int* p, int n) {
    int i = blockIdx.x * 256 + threadIdx.x;
    if (i < n) p[i] = 0;
}

// ---------------- CSR build ----------------
__global__ __launch_bounds__(256) void hist_kernel(const int* __restrict__ dst, int* __restrict__ counts) {
    int e = blockIdx.x * 256 + threadIdx.x;
    if (e < N_EDGES) atomicAdd(&counts[dst[e]], 1);
}

__global__ __launch_bounds__(1024) void scan_kernel(const int* __restrict__ counts, int* __restrict__ indptr, int n) {
    __shared__ int buf[1024];
    __shared__ int carry_s;
    int t = threadIdx.x;
    if (t == 0) { carry_s = 0; indptr[0] = 0; }
    __syncthreads();
    for (int base = 0; base < n; base += 1024) {
        int v = (base + t < n) ? counts[base + t] : 0;
        buf[t] = v;
        __syncthreads();
        for (int off = 1; off < 1024; off <<= 1) {
            int add = (t >= off) ? buf[t - off] : 0;
            __syncthreads();
            buf[t] += add;
            __syncthreads();
        }
        if (base + t < n) indptr[base + t + 1] = carry_s + buf[t];
        __syncthreads();
        if (t == 0) carry_s += buf[1023];
        __syncthreads();
    }
}

__global__ __launch_bounds__(256) void place_kernel(const int* __restrict__ srcp, const int* __restrict__ dstp,
                                                    const int* __restrict__ indptr, int* __restrict__ cursor,
                                                    int* __restrict__ csr_src) {
    int e = blockIdx.x * 256 + threadIdx.x;
    if (e < N_EDGES) {
        int dn = dstp[e];
        int pos = indptr[dn] + atomicAdd(&cursor[dn], 1);
        csr_src[pos] = srcp[e];
    }
}

// ---------------- encoder: h = relu(x @ enc_W + enc_b) ----------------
__global__ __launch_bounds__(256) void encoder_kernel(const float* __restrict__ x, const float* __restrict__ W,
                                                      const float* __restrict__ b, float* __restrict__ h) {
    int gid = blockIdx.x * 256 + threadIdx.x;
    int n = gid >> 7, d = gid & 127;
    if (n >= N_NODES) return;
    float acc = b[d];
#pragma unroll
    for (int f = 0; f < 5; f++) acc += x[n * 5 + f] * W[f * DIM + d];
    h[n * DIM + d] = fmaxf(acc, 0.f);
}

// ---------------- node transform: xl = h@Wl+bl, xr = h@Wr+br ----------------
__global__ __launch_bounds__(256) void transform_kernel(const float* __restrict__ h, const float* __restrict__ Wl,
                                                        const float* __restrict__ bl, const float* __restrict__ Wr,
                                                        const float* __restrict__ br, float* __restrict__ xl,
                                                        float* __restrict__ xr) {
    __shared__ __align__(16) float hs[32][DIM + 1];
    __shared__ __align__(16) float wsh[32][DIM];
    int t = threadIdx.x;
    int n0 = blockIdx.x * 32;
    for (int idx = t; idx < 32 * DIM; idx += 256) {
        int e = idx >> 7, d = idx & 127;
        int n = n0 + e;
        hs[e][d] = (n < N_NODES) ? h[n * DIM + d] : 0.f;
    }
    int d0 = (t & 31) * 4;
    int nb = (t >> 5) * 4;
    float accL[4][4], accR[4][4];
#pragma unroll
    for (int j = 0; j < 4; j++)
#pragma unroll
        for (int i = 0; i < 4; i++) { accL[j][i] = 0.f; accR[j][i] = 0.f; }

#pragma unroll
    for (int half = 0; half < 2; half++) {
        const float* W = half ? Wr : Wl;
        for (int kc = 0; kc < 4; kc++) {
            __syncthreads();
            for (int idx = t; idx < 32 * DIM; idx += 256) {
                int k = idx >> 7, d = idx & 127;
                wsh[k][d] = W[(kc * 32 + k) * DIM + d];
            }
            __syncthreads();
#pragma unroll 8
            for (int k = 0; k < 32; k++) {
                float4 wv = *(const float4*)&wsh[k][d0];
                float hv[4];
#pragma unroll
                for (int j = 0; j < 4; j++) hv[j] = hs[nb + j][kc * 32 + k];
#pragma unroll
                for (int j = 0; j < 4; j++) {
                    if (half == 0) {
                        accL[j][0] += hv[j] * wv.x; accL[j][1] += hv[j] * wv.y;
                        accL[j][2] += hv[j] * wv.z; accL[j][3] += hv[j] * wv.w;
                    } else {
                        accR[j][0] += hv[j] * wv.x; accR[j][1] += hv[j] * wv.y;
                        accR[j][2] += hv[j] * wv.z; accR[j][3] += hv[j] * wv.w;
                    }
                }
            }
        }
    }
#pragma unroll
    for (int j = 0; j < 4; j++) {
        int n = n0 + nb + j;
        if (n < N_NODES) {
#pragma unroll
            for (int i = 0; i < 4; i++) {
                xl[n * DIM + d0 + i] = accL[j][i] + bl[d0 + i];
                xr[n * DIM + d0 + i] = accR[j][i] + br[d0 + i];
            }
        }
    }
}

// ---------------- GATv2 edge+aggregate, one block per node, online softmax ----------------
__global__ __launch_bounds__(128) void gat_edge_kernel(const float* __restrict__ xl, const float* __restrict__ xr,
                                                       const float* __restrict__ att, const float* __restrict__ gbias,
                                                       const int* __restrict__ indptr, const int* __restrict__ csr_src,
                                                       float* __restrict__ h_out) {
    int n = blockIdx.x;
    int t = threadIdx.x;  // t = head*32 + c
    float xrv = xr[n * DIM + t];
    float attv = att[t];
    int beg = indptr[n], end = indptr[n + 1];
    float m = -3.4e38f, den = 0.f, acc = 0.f;
    for (int i = beg; i <= end; ++i) {  // extra iteration = self loop
        int s = (i < end) ? csr_src[i] : n;
        float xlv = xl[s * DIM + t];
        float e = xlv + xrv;
        e = (e > 0.f) ? e : NEG * e;
        float a = e * attv;
        a += __shfl_xor(a, 16);
        a += __shfl_xor(a, 8);
        a += __shfl_xor(a, 4);
        a += __shfl_xor(a, 2);
        a += __shfl_xor(a, 1);
        float mn = fmaxf(m, a);
        float sc = expf(m - mn);
        float p = expf(a - mn);
        den = den * sc + p;
        acc = acc * sc + p * xlv;
        m = mn;
    }
    float o = acc / (den + 1e-16f);
    float v = o + gbias[t];
    h_out[n * DIM + t] = (v > 0.f) ? v : expm1f(v);
}

// ---------------- fused edge classifier: [ni,nj,dt,dist] -> 128 -> 64 -> 1 ----------------
__global__ __launch_bounds__(256) void classifier_kernel(const float* __restrict__ h, const float* __restrict__ x,
                                                         const int* __restrict__ ei, const float* __restrict__ W1,
                                                         const float* __restrict__ b1, const float* __restrict__ W2,
                                                         const float* __restrict__ b2, const float* __restrict__ W3,
                                                         const float* __restrict__ b3, float* __restrict__ out) {
    __shared__ __align__(16) float smA[32 * 260];  // ef tile; later W2 (128*64)
    __shared__ __align__(16) float smB[32 * 129];  // W1 chunk (32*128); later o1 (32*129)
    __shared__ __align__(16) float smC[32 * 65];   // o2
    __shared__ int rowi[32], coli[32];
    int t = threadIdx.x;
    int e0 = blockIdx.x * 32;
    if (t < 32) {
        rowi[t] = ei[e0 + t];
        coli[t] = ei[N_EDGES + e0 + t];
    }
    __syncthreads();
    for (int idx = t; idx < 32 * DIM; idx += 256) {
        int e = idx >> 7, d = idx & 127;
        smA[e * 260 + d] = h[rowi[e] * DIM + d];
        smA[e * 260 + 128 + d] = h[coli[e] * DIM + d];
    }
    if (t < 32) {
        int r = rowi[t], c = coli[t];
        float dt = fabsf(x[r * 5 + 4] - x[c * 5 + 4]);
        float dx = x[r * 5 + 1] - x[c * 5 + 1];
        float dy = x[r * 5 + 2] - x[c * 5 + 2];
        float dz = x[r * 5 + 3] - x[c * 5 + 3];
        smA[t * 260 + 256] = dt;
        smA[t * 260 + 257] = sqrtf(dx * dx + dy * dy + dz * dz);
    }
    int d0 = (t & 31) * 4, eb = (t >> 5) * 4;
    float acc[4][4];
#pragma unroll
    for (int j = 0; j < 4; j++)
#pragma unroll
        for (int i = 0; i < 4; i++) acc[j][i] = 0.f;

    for (int kc = 0; kc < 8; kc++) {
        __syncthreads();
        for (int idx = t; idx < 32 * DIM; idx += 256) {
            int k = idx >> 7, d = idx & 127;
            smB[k * 128 + d] = W1[(kc * 32 + k) * DIM + d];
        }
        __syncthreads();
#pragma unroll 8
        for (int k = 0; k < 32; k++) {
            float4 wv = *(const float4*)&smB[k * 128 + d0];
#pragma unroll
            for (int j = 0; j < 4; j++) {
                float ev = smA[(eb + j) * 260 + kc * 32 + k];
                acc[j][0] += ev * wv.x; acc[j][1] += ev * wv.y;
                acc[j][2] += ev * wv.z; acc[j][3] += ev * wv.w;
            }
        }
    }
    __syncthreads();  // done reading W1 chunk from smB
    // remainder (dt, dist), bias, relu -> o1 into smB [32][129]
#pragma unroll
    for (int j = 0; j < 4; j++) {
        float dt = smA[(eb + j) * 260 + 256];
        float ds = smA[(eb + j) * 260 + 257];
#pragma unroll
        for (int i = 0; i < 4; i++) {
            float v = acc[j][i] + dt * W1[256 * DIM + d0 + i] + ds * W1[257 * DIM + d0 + i] + b1[d0 + i];
            smB[(eb + j) * 129 + d0 + i] = fmaxf(v, 0.f);
        }
    }
    __syncthreads();  // o1 ready; ef (smA) dead
    for (int idx = t; idx < 128 * 64; idx += 256) smA[idx] = W2[idx];
    __syncthreads();
    int j0 = (t & 31) * 2, eb2 = (t >> 5) * 4;
    float a2[4][2];
#pragma unroll
    for (int j = 0; j < 4; j++) { a2[j][0] = 0.f; a2[j][1] = 0.f; }
#pragma unroll 4
    for (int k = 0; k < 128; k++) {
        float2 wv = *(const float2*)&smA[k * 64 + j0];
#pragma unroll
        for (int j = 0; j < 4; j++) {
            float ov = smB[(eb2 + j) * 129 + k];
            a2[j][0] += ov * wv.x;
            a2[j][1] += ov * wv.y;
        }
    }
#pragma unroll
    for (int j = 0; j < 4; j++) {
#pragma unroll
        for (int i = 0; i < 2; i++) {
            float v = a2[j][i] + b2[j0 + i];
            smC[(eb2 + j) * 65 + j0 + i] = fmaxf(v, 0.f);
        }
    }
    __syncthreads();
    if (t < 32) {
        float a3 = b3[0];
#pragma unroll 8
        for (int k = 0; k < 64; k++) a3 += smC[t * 65 + k] * W3[k];
        out[e0 + t] = a3;
    }
}

extern "C" void kernel_launch(void* const* d_in, const int* in_sizes, int n_in,
                              void* d_out, int out_size, void* d_ws, size_t ws_size,
                              hipStream_t stream) {
    const float* x = (const float*)d_in[0];
    const int* ei = (const int*)d_in[1];
    const float* enc_W = (const float*)d_in[2];
    const float* enc_b = (const float*)d_in[3];
    const float* Wl = (const float*)d_in[4];
    const float* bl = (const float*)d_in[5];
    const float* Wr = (const float*)d_in[6];
    const float* br = (const float*)d_in[7];
    const float* att = (const float*)d_in[8];
    const float* gbias = (const float*)d_in[9];
    const float* c1_W = (const float*)d_in[10];
    const float* c1_b = (const float*)d_in[11];
    const float* c2_W = (const float*)d_in[12];
    const float* c2_b = (const float*)d_in[13];
    const float* c3_W = (const float*)d_in[14];
    const float* c3_b = (const float*)d_in[15];
    float* out = (float*)d_out;

    float* h = (float*)d_ws;
    float* xl = h + (size_t)N_NODES * DIM;
    float* xr = xl + (size_t)N_NODES * DIM;
    int* csr_src = (int*)(xr + (size_t)N_NODES * DIM);
    int* indptr = csr_src + N_EDGES;
    int* counts = indptr + (N_NODES + 1);

    const int* srcp = ei;
    const int* dstp = ei + N_EDGES;

    // CSR build (dst is static per call, rebuilt every call for determinism)
    zero_kernel<<<(N_NODES + 255) / 256, 256, 0, stream>>>(counts, N_NODES);
    hist_kernel<<<N_EDGES / 256, 256, 0, stream>>>(dstp, counts);
    scan_kernel<<<1, 1024, 0, stream>>>(counts, indptr, N_NODES);
    zero_kernel<<<(N_NODES + 255) / 256, 256, 0, stream>>>(counts, N_NODES);
    place_kernel<<<N_EDGES / 256, 256, 0, stream>>>(srcp, dstp, indptr, counts, csr_src);

    // encoder
    encoder_kernel<<<(N_NODES * DIM) / 256, 256, 0, stream>>>(x, enc_W, enc_b, h);

    // GAT layers
    for (int i = 0; i < NLAYER; i++) {
        transform_kernel<<<(N_NODES + 31) / 32, 256, 0, stream>>>(
            h, Wl + (size_t)i * DIM * DIM, bl + (size_t)i * DIM,
            Wr + (size_t)i * DIM * DIM, br + (size_t)i * DIM, xl, xr);
        gat_edge_kernel<<<N_NODES, 128, 0, stream>>>(xl, xr, att + (size_t)i * DIM,
                                                     gbias + (size_t)i * DIM, indptr, csr_src, h);
    }

    // edge classifier
    classifier_kernel<<<N_EDGES / 32, 256, 0, stream>>>(h, x, ei, c1_W, c1_b, c2_W, c2_b, c3_W, c3_b, out);
}

// Round 2
// 1343.240 us; speedup vs baseline: 1.8460x; 1.8460x over previous
//
#include <hip/hip_runtime.h>
#include <hip/hip_bf16.h>

#define N_NODES 50000
#define N_EDGES 800000
#define DIM 128
#define NLAYER 3
#define NEG 0.2f

// ---------------- utility ----------------
__global__ __launch_bounds__(256) void zero_kernel(int* p, int n) {
    int i = blockIdx.x * 256 + threadIdx.x;
    if (i < n) p[i] = 0;
}

// ---------------- CSR build ----------------
__global__ __launch_bounds__(256) void hist_kernel(const int* __restrict__ dst, int* __restrict__ counts) {
    int e = blockIdx.x * 256 + threadIdx.x;
    if (e < N_EDGES) atomicAdd(&counts[dst[e]], 1);
}

// hierarchical scan: per-256-chunk inclusive scan + block sums
__global__ __launch_bounds__(256) void scan1_kernel(const int* __restrict__ counts, int* __restrict__ indptr,
                                                    int* __restrict__ bsum, int n) {
    __shared__ int buf[256];
    int t = threadIdx.x;
    int i = blockIdx.x * 256 + t;
    int v = (i < n) ? counts[i] : 0;
    buf[t] = v;
    __syncthreads();
    for (int off = 1; off < 256; off <<= 1) {
        int add = (t >= off) ? buf[t - off] : 0;
        __syncthreads();
        buf[t] += add;
        __syncthreads();
    }
    if (i < n) indptr[i + 1] = buf[t];
    if (t == 255) bsum[blockIdx.x] = buf[255];
}

__global__ __launch_bounds__(256) void scan2_kernel(int* __restrict__ bsum, int* __restrict__ boff,
                                                    int* __restrict__ indptr, int nb) {
    __shared__ int buf[256];
    int t = threadIdx.x;
    int v = (t < nb) ? bsum[t] : 0;
    buf[t] = v;
    __syncthreads();
    for (int off = 1; off < 256; off <<= 1) {
        int add = (t >= off) ? buf[t - off] : 0;
        __syncthreads();
        buf[t] += add;
        __syncthreads();
    }
    if (t < nb) boff[t] = buf[t] - v;  // exclusive
    if (t == 0) indptr[0] = 0;
}

__global__ __launch_bounds__(256) void scan3_kernel(int* __restrict__ indptr, const int* __restrict__ boff, int n) {
    int i = blockIdx.x * 256 + threadIdx.x;
    if (i < n) indptr[i + 1] += boff[i >> 8];
}

__global__ __launch_bounds__(256) void place_kernel(const int* __restrict__ srcp, const int* __restrict__ dstp,
                                                    const int* __restrict__ indptr, int* __restrict__ cursor,
                                                    int* __restrict__ csr_src) {
    int e = blockIdx.x * 256 + threadIdx.x;
    if (e < N_EDGES) {
        int dn = dstp[e];
        int pos = indptr[dn] + atomicAdd(&cursor[dn], 1);
        csr_src[pos] = srcp[e];
    }
}

// ---------------- encoder: h = relu(x @ enc_W + enc_b) ----------------
__global__ __launch_bounds__(256) void encoder_kernel(const float* __restrict__ x, const float* __restrict__ W,
                                                      const float* __restrict__ b, float* __restrict__ h) {
    int gid = blockIdx.x * 256 + threadIdx.x;
    int n = gid >> 7, d = gid & 127;
    if (n >= N_NODES) return;
    float acc = b[d];
#pragma unroll
    for (int f = 0; f < 5; f++) acc += x[n * 5 + f] * W[f * DIM + d];
    h[n * DIM + d] = fmaxf(acc, 0.f);
}

// ---------------- dual GEMM: outA = h@WA (+bA), outB = h@WB (+bB) ----------------
__global__ __launch_bounds__(256) void transform_kernel(const float* __restrict__ h, const float* __restrict__ WA,
                                                        const float* __restrict__ bA, const float* __restrict__ WB,
                                                        const float* __restrict__ bB, float* __restrict__ outA,
                                                        float* __restrict__ outB) {
    __shared__ __align__(16) float hs[32][DIM + 1];
    __shared__ __align__(16) float wsh[32][DIM];
    int t = threadIdx.x;
    int n0 = blockIdx.x * 32;
    for (int idx = t; idx < 32 * DIM; idx += 256) {
        int e = idx >> 7, d = idx & 127;
        int n = n0 + e;
        hs[e][d] = (n < N_NODES) ? h[n * DIM + d] : 0.f;
    }
    int d0 = (t & 31) * 4;
    int nb = (t >> 5) * 4;
    float accL[4][4], accR[4][4];
#pragma unroll
    for (int j = 0; j < 4; j++)
#pragma unroll
        for (int i = 0; i < 4; i++) { accL[j][i] = 0.f; accR[j][i] = 0.f; }

#pragma unroll
    for (int half = 0; half < 2; half++) {
        const float* W = half ? WB : WA;
        for (int kc = 0; kc < 4; kc++) {
            __syncthreads();
            for (int idx = t; idx < 32 * DIM; idx += 256) {
                int k = idx >> 7, d = idx & 127;
                wsh[k][d] = W[(kc * 32 + k) * DIM + d];
            }
            __syncthreads();
#pragma unroll 8
            for (int k = 0; k < 32; k++) {
                float4 wv = *(const float4*)&wsh[k][d0];
                float hv[4];
#pragma unroll
                for (int j = 0; j < 4; j++) hv[j] = hs[nb + j][kc * 32 + k];
#pragma unroll
                for (int j = 0; j < 4; j++) {
                    if (half == 0) {
                        accL[j][0] += hv[j] * wv.x; accL[j][1] += hv[j] * wv.y;
                        accL[j][2] += hv[j] * wv.z; accL[j][3] += hv[j] * wv.w;
                    } else {
                        accR[j][0] += hv[j] * wv.x; accR[j][1] += hv[j] * wv.y;
                        accR[j][2] += hv[j] * wv.z; accR[j][3] += hv[j] * wv.w;
                    }
                }
            }
        }
    }
#pragma unroll
    for (int j = 0; j < 4; j++) {
        int n = n0 + nb + j;
        if (n < N_NODES) {
#pragma unroll
            for (int i = 0; i < 4; i++) {
                float ba = bA ? bA[d0 + i] : 0.f;
                float bb = bB ? bB[d0 + i] : 0.f;
                outA[n * DIM + d0 + i] = accL[j][i] + ba;
                outB[n * DIM + d0 + i] = accR[j][i] + bb;
            }
        }
    }
}

// ---------------- GATv2 edge+aggregate, one block per node, online softmax ----------------
__global__ __launch_bounds__(128) void gat_edge_kernel(const float* __restrict__ xl, const float* __restrict__ xr,
                                                       const float* __restrict__ att, const float* __restrict__ gbias,
                                                       const int* __restrict__ indptr, const int* __restrict__ csr_src,
                                                       float* __restrict__ h_out) {
    int n = blockIdx.x;
    int t = threadIdx.x;  // t = head*32 + c
    float xrv = xr[n * DIM + t];
    float attv = att[t];
    int beg = indptr[n], end = indptr[n + 1];
    float m = -3.4e38f, den = 0.f, acc = 0.f;
    for (int i = beg; i <= end; ++i) {  // extra iteration = self loop
        int s = (i < end) ? csr_src[i] : n;
        float xlv = xl[s * DIM + t];
        float e = xlv + xrv;
        e = (e > 0.f) ? e : NEG * e;
        float a = e * attv;
        a += __shfl_xor(a, 16);
        a += __shfl_xor(a, 8);
        a += __shfl_xor(a, 4);
        a += __shfl_xor(a, 2);
        a += __shfl_xor(a, 1);
        float mn = fmaxf(m, a);
        float sc = expf(m - mn);
        float p = expf(a - mn);
        den = den * sc + p;
        acc = acc * sc + p * xlv;
        m = mn;
    }
    float o = acc / (den + 1e-16f);
    float v = o + gbias[t];
    h_out[n * DIM + t] = (v > 0.f) ? v : expm1f(v);
}

// ---------------- edge MLP: o1 = relu(g1[row]+g2[col]+dt*wdt+dist*wdi); 128->64->1 ----------------
__global__ __launch_bounds__(256) void edge_mlp_kernel(const float* __restrict__ g1, const float* __restrict__ g2,
                                                       const float* __restrict__ x, const int* __restrict__ ei,
                                                       const float* __restrict__ W1tail,  // c1_W rows 256,257
                                                       const float* __restrict__ W2, const float* __restrict__ b2,
                                                       const float* __restrict__ W3, const float* __restrict__ b3,
                                                       float* __restrict__ out, int ntiles) {
    __shared__ __align__(16) float smO1[32][132];
    __shared__ __align__(16) float smW[32][68];
    __shared__ float smCw[2][128];
    __shared__ float smB2[64], smW3[64];
    __shared__ int rowi[32], coli[32];
    __shared__ float sdt[32], sdi[32];
    int t = threadIdx.x;
    if (t < 128) {
        smCw[0][t] = W1tail[t];
        smCw[1][t] = W1tail[128 + t];
    } else if (t < 192) {
        smB2[t - 128] = b2[t - 128];
    } else {
        smW3[t - 192] = W3[t - 192];
    }
    float b3v = b3[0];
    int j0 = (t & 15) * 4;
    int eb = (t >> 4) * 2;
    __syncthreads();

    for (int tile = blockIdx.x; tile < ntiles; tile += gridDim.x) {
        int e0 = tile * 32;
        __syncthreads();  // previous tile fully consumed (smO1, rowi)
        if (t < 32) {
            int r = ei[e0 + t], c = ei[N_EDGES + e0 + t];
            rowi[t] = r; coli[t] = c;
            sdt[t] = fabsf(x[r * 5 + 4] - x[c * 5 + 4]);
            float dx = x[r * 5 + 1] - x[c * 5 + 1];
            float dy = x[r * 5 + 2] - x[c * 5 + 2];
            float dz = x[r * 5 + 3] - x[c * 5 + 3];
            sdi[t] = sqrtf(dx * dx + dy * dy + dz * dz);
        }
        __syncthreads();
        // build o1 tile (g1 carries +b1 already)
        for (int idx = t; idx < 32 * DIM; idx += 256) {
            int e = idx >> 7, d = idx & 127;
            float v = g1[rowi[e] * DIM + d] + g2[coli[e] * DIM + d] + sdt[e] * smCw[0][d] + sdi[e] * smCw[1][d];
            smO1[e][d] = fmaxf(v, 0.f);
        }
        // layer 2: [32 x 128] @ [128 x 64], W2 chunked 32 rows at a time
        float acc[2][4];
#pragma unroll
        for (int j = 0; j < 2; j++)
#pragma unroll
            for (int i = 0; i < 4; i++) acc[j][i] = 0.f;
        for (int kc = 0; kc < 4; kc++) {
            __syncthreads();
            for (int idx = t; idx < 32 * 64; idx += 256) {
                int k = idx >> 6, j = idx & 63;
                smW[k][j] = W2[(kc * 32 + k) * 64 + j];
            }
            __syncthreads();
#pragma unroll 8
            for (int k = 0; k < 32; k++) {
                float4 wv = *(const float4*)&smW[k][j0];
                float a0 = smO1[eb][kc * 32 + k];
                float a1 = smO1[eb + 1][kc * 32 + k];
                acc[0][0] += a0 * wv.x; acc[0][1] += a0 * wv.y;
                acc[0][2] += a0 * wv.z; acc[0][3] += a0 * wv.w;
                acc[1][0] += a1 * wv.x; acc[1][1] += a1 * wv.y;
                acc[1][2] += a1 * wv.z; acc[1][3] += a1 * wv.w;
            }
        }
        // layer 3: relu(o2+b2)·W3, 16-lane shuffle reduce
        float p0 = 0.f, p1 = 0.f;
#pragma unroll
        for (int i = 0; i < 4; i++) {
            float w3 = smW3[j0 + i];
            float bb = smB2[j0 + i];
            p0 += fmaxf(acc[0][i] + bb, 0.f) * w3;
            p1 += fmaxf(acc[1][i] + bb, 0.f) * w3;
        }
        p0 += __shfl_xor(p0, 8); p1 += __shfl_xor(p1, 8);
        p0 += __shfl_xor(p0, 4); p1 += __shfl_xor(p1, 4);
        p0 += __shfl_xor(p0, 2); p1 += __shfl_xor(p1, 2);
        p0 += __shfl_xor(p0, 1); p1 += __shfl_xor(p1, 1);
        if ((t & 15) == 0) {
            out[e0 + eb] = p0 + b3v;
            out[e0 + eb + 1] = p1 + b3v;
        }
    }
}

extern "C" void kernel_launch(void* const* d_in, const int* in_sizes, int n_in,
                              void* d_out, int out_size, void* d_ws, size_t ws_size,
                              hipStream_t stream) {
    const float* x = (const float*)d_in[0];
    const int* ei = (const int*)d_in[1];
    const float* enc_W = (const float*)d_in[2];
    const float* enc_b = (const float*)d_in[3];
    const float* Wl = (const float*)d_in[4];
    const float* bl = (const float*)d_in[5];
    const float* Wr = (const float*)d_in[6];
    const float* br = (const float*)d_in[7];
    const float* att = (const float*)d_in[8];
    const float* gbias = (const float*)d_in[9];
    const float* c1_W = (const float*)d_in[10];
    const float* c1_b = (const float*)d_in[11];
    const float* c2_W = (const float*)d_in[12];
    const float* c2_b = (const float*)d_in[13];
    const float* c3_W = (const float*)d_in[14];
    const float* c3_b = (const float*)d_in[15];
    float* out = (float*)d_out;

    float* h = (float*)d_ws;
    float* xl = h + (size_t)N_NODES * DIM;
    float* xr = xl + (size_t)N_NODES * DIM;
    int* csr_src = (int*)(xr + (size_t)N_NODES * DIM);
    int* indptr = csr_src + N_EDGES;
    int* counts = indptr + (N_NODES + 1);
    int* bsum = counts + N_NODES;
    int* boff = bsum + 256;

    const int* srcp = ei;
    const int* dstp = ei + N_EDGES;
    const int NB = (N_NODES + 255) / 256;  // 196

    // CSR build
    zero_kernel<<<(N_NODES + 255) / 256, 256, 0, stream>>>(counts, N_NODES);
    hist_kernel<<<N_EDGES / 256, 256, 0, stream>>>(dstp, counts);
    scan1_kernel<<<NB, 256, 0, stream>>>(counts, indptr, bsum, N_NODES);
    scan2_kernel<<<1, 256, 0, stream>>>(bsum, boff, indptr, NB);
    scan3_kernel<<<NB, 256, 0, stream>>>(indptr, boff, N_NODES);
    zero_kernel<<<(N_NODES + 255) / 256, 256, 0, stream>>>(counts, N_NODES);
    place_kernel<<<N_EDGES / 256, 256, 0, stream>>>(srcp, dstp, indptr, counts, csr_src);

    // encoder
    encoder_kernel<<<(N_NODES * DIM) / 256, 256, 0, stream>>>(x, enc_W, enc_b, h);

    // GAT layers
    for (int i = 0; i < NLAYER; i++) {
        transform_kernel<<<(N_NODES + 31) / 32, 256, 0, stream>>>(
            h, Wl + (size_t)i * DIM * DIM, bl + (size_t)i * DIM,
            Wr + (size_t)i * DIM * DIM, br + (size_t)i * DIM, xl, xr);
        gat_edge_kernel<<<N_NODES, 128, 0, stream>>>(xl, xr, att + (size_t)i * DIM,
                                                     gbias + (size_t)i * DIM, indptr, csr_src, h);
    }

    // classifier layer-1 node-level split: g1 = h@W1a + b1, g2 = h@W1b  (reuse xl/xr)
    transform_kernel<<<(N_NODES + 31) / 32, 256, 0, stream>>>(
        h, c1_W, c1_b, c1_W + 128 * DIM, nullptr, xl, xr);

    // fused edge MLP
    edge_mlp_kernel<<<2048, 256, 0, stream>>>(xl, xr, x, ei, c1_W + 256 * DIM,
                                              c2_W, c2_b, c3_W, c3_b, out, N_EDGES / 32);
}

// Round 3
// 1104.677 us; speedup vs baseline: 2.2447x; 1.2160x over previous
//
#include <hip/hip_runtime.h>
#include <hip/hip_bf16.h>

#define N_NODES 50000
#define N_EDGES 800000
#define DIM 128
#define NLAYER 3
#define NEG 0.2f

// ---------------- utility ----------------
__global__ __launch_bounds__(256) void zero_kernel(int* p, int n) {
    int i = blockIdx.x * 256 + threadIdx.x;
    if (i < n) p[i] = 0;
}

// ---------------- CSR build ----------------
__global__ __launch_bounds__(256) void hist_kernel(const int* __restrict__ dst, int* __restrict__ counts) {
    int e = blockIdx.x * 256 + threadIdx.x;
    if (e < N_EDGES) atomicAdd(&counts[dst[e]], 1);
}

__global__ __launch_bounds__(256) void scan1_kernel(const int* __restrict__ counts, int* __restrict__ indptr,
                                                    int* __restrict__ bsum, int n) {
    __shared__ int buf[256];
    int t = threadIdx.x;
    int i = blockIdx.x * 256 + t;
    int v = (i < n) ? counts[i] : 0;
    buf[t] = v;
    __syncthreads();
    for (int off = 1; off < 256; off <<= 1) {
        int add = (t >= off) ? buf[t - off] : 0;
        __syncthreads();
        buf[t] += add;
        __syncthreads();
    }
    if (i < n) indptr[i + 1] = buf[t];
    if (t == 255) bsum[blockIdx.x] = buf[255];
}

__global__ __launch_bounds__(256) void scan2_kernel(int* __restrict__ bsum, int* __restrict__ boff,
                                                    int* __restrict__ indptr, int nb) {
    __shared__ int buf[256];
    int t = threadIdx.x;
    int v = (t < nb) ? bsum[t] : 0;
    buf[t] = v;
    __syncthreads();
    for (int off = 1; off < 256; off <<= 1) {
        int add = (t >= off) ? buf[t - off] : 0;
        __syncthreads();
        buf[t] += add;
        __syncthreads();
    }
    if (t < nb) boff[t] = buf[t] - v;  // exclusive
    if (t == 0) indptr[0] = 0;
}

__global__ __launch_bounds__(256) void scan3_kernel(int* __restrict__ indptr, const int* __restrict__ boff, int n) {
    int i = blockIdx.x * 256 + threadIdx.x;
    if (i < n) indptr[i + 1] += boff[i >> 8];
}

__global__ __launch_bounds__(256) void place_kernel(const int* __restrict__ srcp, const int* __restrict__ dstp,
                                                    const int* __restrict__ indptr, int* __restrict__ cursor,
                                                    int* __restrict__ csr_src) {
    int e = blockIdx.x * 256 + threadIdx.x;
    if (e < N_EDGES) {
        int dn = dstp[e];
        int pos = indptr[dn] + atomicAdd(&cursor[dn], 1);
        csr_src[pos] = srcp[e];
    }
}

// ---------------- encoder: h = relu(x @ enc_W + enc_b) ----------------
__global__ __launch_bounds__(256) void encoder_kernel(const float* __restrict__ x, const float* __restrict__ W,
                                                      const float* __restrict__ b, float* __restrict__ h) {
    int gid = blockIdx.x * 256 + threadIdx.x;
    int n = gid >> 7, d = gid & 127;
    if (n >= N_NODES) return;
    float acc = b[d];
#pragma unroll
    for (int f = 0; f < 5; f++) acc += x[n * 5 + f] * W[f * DIM + d];
    h[n * DIM + d] = fmaxf(acc, 0.f);
}

// ---------------- dual GEMM: outA = h@WA (+bA), outB = h@WB (+bB) ----------------
// BF16OUT: store outputs rounded to bf16 (fp32 accumulate throughout)
template <bool BF16OUT>
__global__ __launch_bounds__(256) void transform_kernel(const float* __restrict__ h, const float* __restrict__ WA,
                                                        const float* __restrict__ bA, const float* __restrict__ WB,
                                                        const float* __restrict__ bB, void* __restrict__ outA_,
                                                        void* __restrict__ outB_) {
    __shared__ __align__(16) float hs[32][DIM + 1];
    __shared__ __align__(16) float wsh[32][DIM];
    int t = threadIdx.x;
    int n0 = blockIdx.x * 32;
    for (int idx = t; idx < 32 * DIM; idx += 256) {
        int e = idx >> 7, d = idx & 127;
        int n = n0 + e;
        hs[e][d] = (n < N_NODES) ? h[n * DIM + d] : 0.f;
    }
    int d0 = (t & 31) * 4;
    int nb = (t >> 5) * 4;
    float accL[4][4], accR[4][4];
#pragma unroll
    for (int j = 0; j < 4; j++)
#pragma unroll
        for (int i = 0; i < 4; i++) { accL[j][i] = 0.f; accR[j][i] = 0.f; }

#pragma unroll
    for (int half = 0; half < 2; half++) {
        const float* W = half ? WB : WA;
        for (int kc = 0; kc < 4; kc++) {
            __syncthreads();
            for (int idx = t; idx < 32 * DIM; idx += 256) {
                int k = idx >> 7, d = idx & 127;
                wsh[k][d] = W[(kc * 32 + k) * DIM + d];
            }
            __syncthreads();
#pragma unroll 8
            for (int k = 0; k < 32; k++) {
                float4 wv = *(const float4*)&wsh[k][d0];
                float hv[4];
#pragma unroll
                for (int j = 0; j < 4; j++) hv[j] = hs[nb + j][kc * 32 + k];
#pragma unroll
                for (int j = 0; j < 4; j++) {
                    if (half == 0) {
                        accL[j][0] += hv[j] * wv.x; accL[j][1] += hv[j] * wv.y;
                        accL[j][2] += hv[j] * wv.z; accL[j][3] += hv[j] * wv.w;
                    } else {
                        accR[j][0] += hv[j] * wv.x; accR[j][1] += hv[j] * wv.y;
                        accR[j][2] += hv[j] * wv.z; accR[j][3] += hv[j] * wv.w;
                    }
                }
            }
        }
    }
#pragma unroll
    for (int j = 0; j < 4; j++) {
        int n = n0 + nb + j;
        if (n < N_NODES) {
#pragma unroll
            for (int i = 0; i < 4; i++) {
                float ba = bA ? bA[d0 + i] : 0.f;
                float bb = bB ? bB[d0 + i] : 0.f;
                float va = accL[j][i] + ba;
                float vb = accR[j][i] + bb;
                if constexpr (BF16OUT) {
                    __hip_bfloat16* oA = (__hip_bfloat16*)outA_;
                    __hip_bfloat16* oB = (__hip_bfloat16*)outB_;
                    oA[n * DIM + d0 + i] = __float2bfloat16(va);
                    oB[n * DIM + d0 + i] = __float2bfloat16(vb);
                } else {
                    float* oA = (float*)outA_;
                    float* oB = (float*)outB_;
                    oA[n * DIM + d0 + i] = va;
                    oB[n * DIM + d0 + i] = vb;
                }
            }
        }
    }
}

// ---------------- GATv2 edge+aggregate: self-loop first, 2-way ILP online softmax ----------------
__global__ __launch_bounds__(128) void gat_edge_kernel(const float* __restrict__ xl, const float* __restrict__ xr,
                                                       const float* __restrict__ att, const float* __restrict__ gbias,
                                                       const int* __restrict__ indptr, const int* __restrict__ csr_src,
                                                       float* __restrict__ h_out) {
    int n = blockIdx.x;
    int t = threadIdx.x;  // t = head*32 + c
    float xrv = xr[n * DIM + t];
    float attv = att[t];
    int beg = indptr[n], end = indptr[n + 1];

    // self-loop seeds chain 0
    float xls = xl[n * DIM + t];
    float es = xls + xrv;
    es = (es > 0.f) ? es : NEG * es;
    float as_ = es * attv;
    as_ += __shfl_xor(as_, 16);
    as_ += __shfl_xor(as_, 8);
    as_ += __shfl_xor(as_, 4);
    as_ += __shfl_xor(as_, 2);
    as_ += __shfl_xor(as_, 1);
    float m0 = as_, den0 = 1.f, acc0 = xls;
    float m1 = -3.4e38f, den1 = 0.f, acc1 = 0.f;

    int i = beg;
    for (; i + 2 <= end; i += 2) {
        int s0 = csr_src[i], s1 = csr_src[i + 1];
        float v0 = xl[s0 * DIM + t];
        float v1 = xl[s1 * DIM + t];
        float e0 = v0 + xrv; e0 = (e0 > 0.f) ? e0 : NEG * e0;
        float e1 = v1 + xrv; e1 = (e1 > 0.f) ? e1 : NEG * e1;
        float a0 = e0 * attv, a1 = e1 * attv;
        a0 += __shfl_xor(a0, 16); a1 += __shfl_xor(a1, 16);
        a0 += __shfl_xor(a0, 8);  a1 += __shfl_xor(a1, 8);
        a0 += __shfl_xor(a0, 4);  a1 += __shfl_xor(a1, 4);
        a0 += __shfl_xor(a0, 2);  a1 += __shfl_xor(a1, 2);
        a0 += __shfl_xor(a0, 1);  a1 += __shfl_xor(a1, 1);
        float mn0 = fmaxf(m0, a0);
        float mn1 = fmaxf(m1, a1);
        float sc0 = __expf(m0 - mn0), p0 = __expf(a0 - mn0);
        float sc1 = __expf(m1 - mn1), p1 = __expf(a1 - mn1);
        den0 = den0 * sc0 + p0;
        den1 = den1 * sc1 + p1;
        acc0 = acc0 * sc0 + p0 * v0;
        acc1 = acc1 * sc1 + p1 * v1;
        m0 = mn0; m1 = mn1;
    }
    if (i < end) {
        int s0 = csr_src[i];
        float v0 = xl[s0 * DIM + t];
        float e0 = v0 + xrv; e0 = (e0 > 0.f) ? e0 : NEG * e0;
        float a0 = e0 * attv;
        a0 += __shfl_xor(a0, 16);
        a0 += __shfl_xor(a0, 8);
        a0 += __shfl_xor(a0, 4);
        a0 += __shfl_xor(a0, 2);
        a0 += __shfl_xor(a0, 1);
        float mn0 = fmaxf(m0, a0);
        float sc0 = __expf(m0 - mn0), p0 = __expf(a0 - mn0);
        den0 = den0 * sc0 + p0;
        acc0 = acc0 * sc0 + p0 * v0;
        m0 = mn0;
    }
    // merge the two chains
    float m = fmaxf(m0, m1);
    float s0 = __expf(m0 - m), s1 = __expf(m1 - m);
    float den = den0 * s0 + den1 * s1;
    float acc = acc0 * s0 + acc1 * s1;

    float o = acc / (den + 1e-16f);
    float v = o + gbias[t];
    h_out[n * DIM + t] = (v > 0.f) ? v : __expf(v) - 1.f;
}

// ---------------- edge MLP: o1 = relu(g1[row]+g2[col]+dt*wdt+dist*wdi); 128->64->1 ----------------
// g1/g2 are bf16 [N][128]; W2 resident in LDS (fp32); 3 syncs per 32-edge tile
__global__ __launch_bounds__(256) void edge_mlp_kernel(const unsigned* __restrict__ g1u, const unsigned* __restrict__ g2u,
                                                       const float* __restrict__ x, const int* __restrict__ ei,
                                                       const float* __restrict__ W1tail,  // c1_W rows 256,257
                                                       const float* __restrict__ W2, const float* __restrict__ b2,
                                                       const float* __restrict__ W3, const float* __restrict__ b3,
                                                       float* __restrict__ out, int ntiles) {
    __shared__ __align__(16) float smW[128][64];   // W2 resident
    __shared__ __align__(16) float smO1[32][132];
    __shared__ float smCw[2][128];
    __shared__ float smB2[64], smW3[64];
    __shared__ int rowi[32], coli[32];
    __shared__ float sdt[32], sdi[32];
    int t = threadIdx.x;
    // one-time LDS fill (visibility guaranteed by first in-loop sync)
    for (int idx = t; idx < 128 * 64; idx += 256) ((float*)smW)[idx] = W2[idx];
    if (t < 128) {
        smCw[0][t] = W1tail[t];
        smCw[1][t] = W1tail[128 + t];
    } else if (t < 192) {
        smB2[t - 128] = b2[t - 128];
    } else {
        smW3[t - 192] = W3[t - 192];
    }
    float b3v = b3[0];
    int j0 = (t & 15) * 4;
    int eb = (t >> 4) * 2;

    for (int tile = blockIdx.x; tile < ntiles; tile += gridDim.x) {
        int e0 = tile * 32;
        __syncthreads();  // prev tile consumed; first iter: LDS prefill visible
        if (t < 32) {
            int r = ei[e0 + t], c = ei[N_EDGES + e0 + t];
            rowi[t] = r; coli[t] = c;
            sdt[t] = fabsf(x[r * 5 + 4] - x[c * 5 + 4]);
            float dx = x[r * 5 + 1] - x[c * 5 + 1];
            float dy = x[r * 5 + 2] - x[c * 5 + 2];
            float dz = x[r * 5 + 3] - x[c * 5 + 3];
            sdi[t] = sqrtf(dx * dx + dy * dy + dz * dz);
        }
        __syncthreads();
        // build o1 tile: 2 bf16 dims per iteration (4B gathers)
        for (int idx = t; idx < 32 * 64; idx += 256) {
            int e = idx >> 6, dp = idx & 63;
            int d = dp * 2;
            unsigned u1 = g1u[rowi[e] * 64 + dp];
            unsigned u2 = g2u[coli[e] * 64 + dp];
            float glo = __uint_as_float(u1 << 16) + __uint_as_float(u2 << 16);
            float ghi = __uint_as_float(u1 & 0xffff0000u) + __uint_as_float(u2 & 0xffff0000u);
            float dtv = sdt[e], div = sdi[e];
            float vlo = glo + dtv * smCw[0][d] + div * smCw[1][d];
            float vhi = ghi + dtv * smCw[0][d + 1] + div * smCw[1][d + 1];
            smO1[e][d] = fmaxf(vlo, 0.f);
            smO1[e][d + 1] = fmaxf(vhi, 0.f);
        }
        __syncthreads();
        // layer 2: [32 x 128] @ [128 x 64], W2 resident
        float acc[2][4];
#pragma unroll
        for (int j = 0; j < 2; j++)
#pragma unroll
            for (int i = 0; i < 4; i++) acc[j][i] = 0.f;
#pragma unroll 8
        for (int k = 0; k < 128; k++) {
            float4 wv = *(const float4*)&smW[k][j0];
            float a0 = smO1[eb][k];
            float a1 = smO1[eb + 1][k];
            acc[0][0] += a0 * wv.x; acc[0][1] += a0 * wv.y;
            acc[0][2] += a0 * wv.z; acc[0][3] += a0 * wv.w;
            acc[1][0] += a1 * wv.x; acc[1][1] += a1 * wv.y;
            acc[1][2] += a1 * wv.z; acc[1][3] += a1 * wv.w;
        }
        // layer 3: relu(o2+b2)·W3, 16-lane shuffle reduce
        float p0 = 0.f, p1 = 0.f;
#pragma unroll
        for (int i = 0; i < 4; i++) {
            float w3 = smW3[j0 + i];
            float bb = smB2[j0 + i];
            p0 += fmaxf(acc[0][i] + bb, 0.f) * w3;
            p1 += fmaxf(acc[1][i] + bb, 0.f) * w3;
        }
        p0 += __shfl_xor(p0, 8); p1 += __shfl_xor(p1, 8);
        p0 += __shfl_xor(p0, 4); p1 += __shfl_xor(p1, 4);
        p0 += __shfl_xor(p0, 2); p1 += __shfl_xor(p1, 2);
        p0 += __shfl_xor(p0, 1); p1 += __shfl_xor(p1, 1);
        if ((t & 15) == 0) {
            out[e0 + eb] = p0 + b3v;
            out[e0 + eb + 1] = p1 + b3v;
        }
    }
}

extern "C" void kernel_launch(void* const* d_in, const int* in_sizes, int n_in,
                              void* d_out, int out_size, void* d_ws, size_t ws_size,
                              hipStream_t stream) {
    const float* x = (const float*)d_in[0];
    const int* ei = (const int*)d_in[1];
    const float* enc_W = (const float*)d_in[2];
    const float* enc_b = (const float*)d_in[3];
    const float* Wl = (const float*)d_in[4];
    const float* bl = (const float*)d_in[5];
    const float* Wr = (const float*)d_in[6];
    const float* br = (const float*)d_in[7];
    const float* att = (const float*)d_in[8];
    const float* gbias = (const float*)d_in[9];
    const float* c1_W = (const float*)d_in[10];
    const float* c1_b = (const float*)d_in[11];
    const float* c2_W = (const float*)d_in[12];
    const float* c2_b = (const float*)d_in[13];
    const float* c3_W = (const float*)d_in[14];
    const float* c3_b = (const float*)d_in[15];
    float* out = (float*)d_out;

    float* h = (float*)d_ws;
    float* xl = h + (size_t)N_NODES * DIM;
    float* xr = xl + (size_t)N_NODES * DIM;
    int* csr_src = (int*)(xr + (size_t)N_NODES * DIM);
    int* indptr = csr_src + N_EDGES;
    int* counts = indptr + (N_NODES + 1);
    int* bsum = counts + N_NODES;
    int* boff = bsum + 256;

    const int* srcp = ei;
    const int* dstp = ei + N_EDGES;
    const int NB = (N_NODES + 255) / 256;  // 196

    // CSR build
    zero_kernel<<<(N_NODES + 255) / 256, 256, 0, stream>>>(counts, N_NODES);
    hist_kernel<<<N_EDGES / 256, 256, 0, stream>>>(dstp, counts);
    scan1_kernel<<<NB, 256, 0, stream>>>(counts, indptr, bsum, N_NODES);
    scan2_kernel<<<1, 256, 0, stream>>>(bsum, boff, indptr, NB);
    scan3_kernel<<<NB, 256, 0, stream>>>(indptr, boff, N_NODES);
    zero_kernel<<<(N_NODES + 255) / 256, 256, 0, stream>>>(counts, N_NODES);
    place_kernel<<<N_EDGES / 256, 256, 0, stream>>>(srcp, dstp, indptr, counts, csr_src);

    // encoder
    encoder_kernel<<<(N_NODES * DIM) / 256, 256, 0, stream>>>(x, enc_W, enc_b, h);

    // GAT layers (fp32 xl/xr)
    for (int i = 0; i < NLAYER; i++) {
        transform_kernel<false><<<(N_NODES + 31) / 32, 256, 0, stream>>>(
            h, Wl + (size_t)i * DIM * DIM, bl + (size_t)i * DIM,
            Wr + (size_t)i * DIM * DIM, br + (size_t)i * DIM, xl, xr);
        gat_edge_kernel<<<N_NODES, 128, 0, stream>>>(xl, xr, att + (size_t)i * DIM,
                                                     gbias + (size_t)i * DIM, indptr, csr_src, h);
    }

    // classifier layer-1 node-level split: g1 = h@W1a + b1, g2 = h@W1b (bf16 storage; reuse xl/xr space)
    transform_kernel<true><<<(N_NODES + 31) / 32, 256, 0, stream>>>(
        h, c1_W, c1_b, c1_W + 128 * DIM, nullptr, xl, xr);

    // fused edge MLP
    edge_mlp_kernel<<<1536, 256, 0, stream>>>((const unsigned*)xl, (const unsigned*)xr, x, ei,
                                              c1_W + 256 * DIM, c2_W, c2_b, c3_W, c3_b, out, N_EDGES / 32);
}

// Round 4
// 1013.487 us; speedup vs baseline: 2.4467x; 1.0900x over previous
//
#include <hip/hip_runtime.h>
#include <hip/hip_bf16.h>

#define N_NODES 50000
#define N_EDGES 800000
#define DIM 128
#define NLAYER 3
#define NEG 0.2f

typedef __attribute__((ext_vector_type(8))) short short8;
typedef __attribute__((ext_vector_type(4))) float f32x4;

// ---------------- utility ----------------
__global__ __launch_bounds__(256) void zero_kernel(int* p, int n) {
    int i = blockIdx.x * 256 + threadIdx.x;
    if (i < n) p[i] = 0;
}

// ---------------- CSR build ----------------
__global__ __launch_bounds__(256) void hist_kernel(const int* __restrict__ dst, int* __restrict__ counts) {
    int e = blockIdx.x * 256 + threadIdx.x;
    if (e < N_EDGES) atomicAdd(&counts[dst[e]], 1);
}

__global__ __launch_bounds__(256) void scan1_kernel(const int* __restrict__ counts, int* __restrict__ indptr,
                                                    int* __restrict__ bsum, int n) {
    __shared__ int buf[256];
    int t = threadIdx.x;
    int i = blockIdx.x * 256 + t;
    int v = (i < n) ? counts[i] : 0;
    buf[t] = v;
    __syncthreads();
    for (int off = 1; off < 256; off <<= 1) {
        int add = (t >= off) ? buf[t - off] : 0;
        __syncthreads();
        buf[t] += add;
        __syncthreads();
    }
    if (i < n) indptr[i + 1] = buf[t];
    if (t == 255) bsum[blockIdx.x] = buf[255];
}

__global__ __launch_bounds__(256) void scan2_kernel(int* __restrict__ bsum, int* __restrict__ boff,
                                                    int* __restrict__ indptr, int nb) {
    __shared__ int buf[256];
    int t = threadIdx.x;
    int v = (t < nb) ? bsum[t] : 0;
    buf[t] = v;
    __syncthreads();
    for (int off = 1; off < 256; off <<= 1) {
        int add = (t >= off) ? buf[t - off] : 0;
        __syncthreads();
        buf[t] += add;
        __syncthreads();
    }
    if (t < nb) boff[t] = buf[t] - v;  // exclusive
    if (t == 0) indptr[0] = 0;
}

__global__ __launch_bounds__(256) void scan3_kernel(int* __restrict__ indptr, const int* __restrict__ boff, int n) {
    int i = blockIdx.x * 256 + threadIdx.x;
    if (i < n) indptr[i + 1] += boff[i >> 8];
}

__global__ __launch_bounds__(256) void place_kernel(const int* __restrict__ srcp, const int* __restrict__ dstp,
                                                    const int* __restrict__ indptr, int* __restrict__ cursor,
                                                    int* __restrict__ csr_src) {
    int e = blockIdx.x * 256 + threadIdx.x;
    if (e < N_EDGES) {
        int dn = dstp[e];
        int pos = indptr[dn] + atomicAdd(&cursor[dn], 1);
        csr_src[pos] = srcp[e];
    }
}

// ---------------- encoder: h = relu(x @ enc_W + enc_b) ----------------
__global__ __launch_bounds__(256) void encoder_kernel(const float* __restrict__ x, const float* __restrict__ W,
                                                      const float* __restrict__ b, float* __restrict__ h) {
    int gid = blockIdx.x * 256 + threadIdx.x;
    int n = gid >> 7, d = gid & 127;
    if (n >= N_NODES) return;
    float acc = b[d];
#pragma unroll
    for (int f = 0; f < 5; f++) acc += x[n * 5 + f] * W[f * DIM + d];
    h[n * DIM + d] = fmaxf(acc, 0.f);
}

// ---------------- dual GEMM v2: 64-node tile, 8x4 per-thread, broadcast h reads ----------------
template <bool BF16OUT>
__global__ __launch_bounds__(256) void transform_kernel(const float* __restrict__ h, const float* __restrict__ WA,
                                                        const float* __restrict__ bA, const float* __restrict__ WB,
                                                        const float* __restrict__ bB, void* __restrict__ outA_,
                                                        void* __restrict__ outB_) {
    __shared__ __align__(16) float hs[64][DIM];   // 32 KB
    __shared__ __align__(16) float wsh[32][DIM];  // 16 KB
    int t = threadIdx.x;
    int n0 = blockIdx.x * 64;
    // stage h tile (coalesced float4)
    for (int i = t; i < 64 * 32; i += 256) {
        int row = i >> 5, c4 = (i & 31) * 4;
        int n = n0 + row;
        float4 v = make_float4(0.f, 0.f, 0.f, 0.f);
        if (n < N_NODES) v = *(const float4*)&h[(size_t)n * DIM + c4];
        *(float4*)&hs[row][c4] = v;
    }
    int d0 = (t & 31) * 4;
    int r0 = (t >> 5) * 8;
    float accL[8][4], accR[8][4];
#pragma unroll
    for (int j = 0; j < 8; j++)
#pragma unroll
        for (int i = 0; i < 4; i++) { accL[j][i] = 0.f; accR[j][i] = 0.f; }

#pragma unroll
    for (int half = 0; half < 2; half++) {
        const float* W = half ? WB : WA;
        for (int kc = 0; kc < 4; kc++) {
            __syncthreads();
            for (int i = t; i < 32 * 32; i += 256) {
                int k = i >> 5, c4 = (i & 31) * 4;
                *(float4*)&wsh[k][c4] = *(const float4*)&W[(size_t)(kc * 32 + k) * DIM + c4];
            }
            __syncthreads();
#pragma unroll
            for (int k4 = 0; k4 < 8; k4++) {
                float4 wv[4];
#pragma unroll
                for (int kk = 0; kk < 4; kk++) wv[kk] = *(const float4*)&wsh[k4 * 4 + kk][d0];
#pragma unroll
                for (int j = 0; j < 8; j++) {
                    float4 hv = *(const float4*)&hs[r0 + j][kc * 32 + k4 * 4];
                    float* a = half ? accR[j] : accL[j];
                    a[0] += hv.x * wv[0].x + hv.y * wv[1].x + hv.z * wv[2].x + hv.w * wv[3].x;
                    a[1] += hv.x * wv[0].y + hv.y * wv[1].y + hv.z * wv[2].y + hv.w * wv[3].y;
                    a[2] += hv.x * wv[0].z + hv.y * wv[1].z + hv.z * wv[2].z + hv.w * wv[3].z;
                    a[3] += hv.x * wv[0].w + hv.y * wv[1].w + hv.z * wv[2].w + hv.w * wv[3].w;
                }
            }
        }
    }
#pragma unroll
    for (int j = 0; j < 8; j++) {
        int n = n0 + r0 + j;
        if (n < N_NODES) {
#pragma unroll
            for (int i = 0; i < 4; i++) {
                float ba = bA ? bA[d0 + i] : 0.f;
                float bb = bB ? bB[d0 + i] : 0.f;
                float va = accL[j][i] + ba;
                float vb = accR[j][i] + bb;
                if constexpr (BF16OUT) {
                    __hip_bfloat16* oA = (__hip_bfloat16*)outA_;
                    __hip_bfloat16* oB = (__hip_bfloat16*)outB_;
                    oA[(size_t)n * DIM + d0 + i] = __float2bfloat16(va);
                    oB[(size_t)n * DIM + d0 + i] = __float2bfloat16(vb);
                } else {
                    float* oA = (float*)outA_;
                    float* oB = (float*)outB_;
                    oA[(size_t)n * DIM + d0 + i] = va;
                    oB[(size_t)n * DIM + d0 + i] = vb;
                }
            }
        }
    }
}

// ---------------- GATv2 edge+aggregate: self-loop seed, 4-way ILP online softmax ----------------
__device__ __forceinline__ float head_reduce(float a) {
    a += __shfl_xor(a, 16);
    a += __shfl_xor(a, 8);
    a += __shfl_xor(a, 4);
    a += __shfl_xor(a, 2);
    a += __shfl_xor(a, 1);
    return a;
}

__global__ __launch_bounds__(128) void gat_edge_kernel(const float* __restrict__ xl, const float* __restrict__ xr,
                                                       const float* __restrict__ att, const float* __restrict__ gbias,
                                                       const int* __restrict__ indptr, const int* __restrict__ csr_src,
                                                       float* __restrict__ h_out) {
    int n = blockIdx.x;
    int t = threadIdx.x;  // t = head*32 + c
    float xrv = xr[n * DIM + t];
    float attv = att[t];
    int beg = indptr[n], end = indptr[n + 1];

    // self-loop seeds chain 0
    float xls = xl[n * DIM + t];
    float es = xls + xrv;
    es = (es > 0.f) ? es : NEG * es;
    float m[4], den[4], acc[4];
    m[0] = head_reduce(es * attv); den[0] = 1.f; acc[0] = xls;
#pragma unroll
    for (int c = 1; c < 4; c++) { m[c] = -3.4e38f; den[c] = 0.f; acc[c] = 0.f; }

    int i = beg;
    for (; i + 4 <= end; i += 4) {
        int s[4];
        float v[4], a[4];
#pragma unroll
        for (int c = 0; c < 4; c++) s[c] = csr_src[i + c];
#pragma unroll
        for (int c = 0; c < 4; c++) v[c] = xl[s[c] * DIM + t];
#pragma unroll
        for (int c = 0; c < 4; c++) {
            float e = v[c] + xrv;
            e = (e > 0.f) ? e : NEG * e;
            a[c] = e * attv;
        }
#pragma unroll
        for (int off = 16; off >= 1; off >>= 1)
#pragma unroll
            for (int c = 0; c < 4; c++) a[c] += __shfl_xor(a[c], off);
#pragma unroll
        for (int c = 0; c < 4; c++) {
            float mn = fmaxf(m[c], a[c]);
            float sc = __expf(m[c] - mn), p = __expf(a[c] - mn);
            den[c] = den[c] * sc + p;
            acc[c] = acc[c] * sc + p * v[c];
            m[c] = mn;
        }
    }
    for (; i < end; ++i) {
        int s0 = csr_src[i];
        float v0 = xl[s0 * DIM + t];
        float e0 = v0 + xrv;
        e0 = (e0 > 0.f) ? e0 : NEG * e0;
        float a0 = head_reduce(e0 * attv);
        float mn = fmaxf(m[0], a0);
        float sc = __expf(m[0] - mn), p = __expf(a0 - mn);
        den[0] = den[0] * sc + p;
        acc[0] = acc[0] * sc + p * v0;
        m[0] = mn;
    }
    // merge 4 chains
    float mm = fmaxf(fmaxf(m[0], m[1]), fmaxf(m[2], m[3]));
    float dd = 0.f, aa = 0.f;
#pragma unroll
    for (int c = 0; c < 4; c++) {
        float sc = __expf(m[c] - mm);
        dd += den[c] * sc;
        aa += acc[c] * sc;
    }
    float o = aa / (dd + 1e-16f);
    float v = o + gbias[t];
    h_out[n * DIM + t] = (v > 0.f) ? v : __expf(v) - 1.f;
}

// ---------------- edge MLP v3: bf16 MFMA layer2, 64-edge tiles ----------------
// o1[e][d] = relu(g1[row]+g2[col]+dt*w+di*w) stored bf16 swizzled; O2 = o1@W2 via MFMA; layer3 shfl-reduce
__global__ __launch_bounds__(256) void edge_mlp_kernel(const unsigned* __restrict__ g1u, const unsigned* __restrict__ g2u,
                                                       const float* __restrict__ x, const int* __restrict__ ei,
                                                       const float* __restrict__ W1tail,  // c1_W rows 256,257
                                                       const float* __restrict__ W2, const float* __restrict__ b2,
                                                       const float* __restrict__ W3, const float* __restrict__ b3,
                                                       float* __restrict__ out, int ntiles) {
    __shared__ __align__(16) char smO1[64 * 256];   // 64 edges x 128 bf16, XOR-swizzled 16B
    __shared__ __align__(16) char smW2T[64 * 256];  // W2^T: [n][k] bf16, XOR-swizzled 16B
    __shared__ float smCw[2][128];
    __shared__ float smPart[4][64];
    __shared__ int rowi[64], coli[64];
    __shared__ float sdt[64], sdi[64];
    int t = threadIdx.x;
    int l = t & 63, w = t >> 6;

    // one-time: W2^T -> bf16 swizzled LDS (visibility via in-loop syncs)
    for (int idx = t; idx < 128 * 64; idx += 256) {
        int k = idx >> 6, n = idx & 63;
        __hip_bfloat16 bv = __float2bfloat16(W2[idx]);
        unsigned short us = *reinterpret_cast<unsigned short*>(&bv);
        int addr = (n * 256 + k * 2) ^ ((n & 7) << 4);
        *(unsigned short*)(smW2T + addr) = us;
    }
    if (t < 128) {
        smCw[0][t] = W1tail[t];
        smCw[1][t] = W1tail[128 + t];
    }
    float b3v = b3[0];
    float b2v = b2[w * 16 + (l & 15)];
    float w3v = W3[w * 16 + (l & 15)];
    int koff = (l >> 4) * 16;  // byte offset of k-group in a 256B row

    for (int tile = blockIdx.x; tile < ntiles; tile += gridDim.x) {
        int e0 = tile * 64;
        __syncthreads();  // prev tile fully consumed (also first-iter LDS prefill fence)
        if (t < 64) {
            int r = ei[e0 + t], c = ei[N_EDGES + e0 + t];
            rowi[t] = r; coli[t] = c;
            sdt[t] = fabsf(x[r * 5 + 4] - x[c * 5 + 4]);
            float dx = x[r * 5 + 1] - x[c * 5 + 1];
            float dy = x[r * 5 + 2] - x[c * 5 + 2];
            float dz = x[r * 5 + 3] - x[c * 5 + 3];
            sdi[t] = sqrtf(dx * dx + dy * dy + dz * dz);
        }
        __syncthreads();
        // build o1: each thread handles one 16B slot (8 dims) of one edge
        for (int idx = t; idx < 64 * 16; idx += 256) {
            int e = idx >> 4, s4 = idx & 15;
            const uint4* p1 = (const uint4*)(g1u + rowi[e] * 64);
            const uint4* p2 = (const uint4*)(g2u + coli[e] * 64);
            uint4 u1 = p1[s4], u2 = p2[s4];
            float dtv = sdt[e], div = sdi[e];
            unsigned uo[4];
            const unsigned* a1 = &u1.x;
            const unsigned* a2 = &u2.x;
#pragma unroll
            for (int q = 0; q < 4; q++) {
                int d = s4 * 8 + q * 2;
                float lo = __uint_as_float(a1[q] << 16) + __uint_as_float(a2[q] << 16) + dtv * smCw[0][d] + div * smCw[1][d];
                float hi = __uint_as_float(a1[q] & 0xffff0000u) + __uint_as_float(a2[q] & 0xffff0000u) +
                           dtv * smCw[0][d + 1] + div * smCw[1][d + 1];
                lo = fmaxf(lo, 0.f); hi = fmaxf(hi, 0.f);
                __hip_bfloat16 blo = __float2bfloat16(lo), bhi = __float2bfloat16(hi);
                unsigned short ulo = *reinterpret_cast<unsigned short*>(&blo);
                unsigned short uhi = *reinterpret_cast<unsigned short*>(&bhi);
                uo[q] = (unsigned)ulo | ((unsigned)uhi << 16);
            }
            int addr = (e * 256 + s4 * 16) ^ ((e & 7) << 4);
            *(uint4*)(smO1 + addr) = *(uint4*)uo;
        }
        __syncthreads();
        // layer 2 via MFMA: wave w owns n-tile w (cols w*16..+15); 4 m-tiles
        f32x4 acc[4];
#pragma unroll
        for (int mt = 0; mt < 4; mt++) acc[mt] = (f32x4){0.f, 0.f, 0.f, 0.f};
        int nrow = w * 16 + (l & 15);
#pragma unroll
        for (int ks = 0; ks < 4; ks++) {
            short8 bfrag = *(const short8*)(smW2T + ((nrow * 256 + koff + ks * 64) ^ ((nrow & 7) << 4)));
#pragma unroll
            for (int mt = 0; mt < 4; mt++) {
                int mrow = mt * 16 + (l & 15);
                short8 afrag = *(const short8*)(smO1 + ((mrow * 256 + koff + ks * 64) ^ ((mrow & 7) << 4)));
                acc[mt] = __builtin_amdgcn_mfma_f32_16x16x32_bf16(afrag, bfrag, acc[mt], 0, 0, 0);
            }
        }
        // layer 3: p[m] = sum_n relu(O2[m][n]+b2[n])*W3[n]; reduce over 16 lanes (n)
        float p[4][4];
#pragma unroll
        for (int mt = 0; mt < 4; mt++)
#pragma unroll
            for (int r = 0; r < 4; r++) p[mt][r] = fmaxf(acc[mt][r] + b2v, 0.f) * w3v;
#pragma unroll
        for (int off = 8; off >= 1; off >>= 1)
#pragma unroll
            for (int mt = 0; mt < 4; mt++)
#pragma unroll
                for (int r = 0; r < 4; r++) p[mt][r] += __shfl_xor(p[mt][r], off);
        if ((l & 15) == 0) {
            int g = l >> 4;
#pragma unroll
            for (int mt = 0; mt < 4; mt++)
#pragma unroll
                for (int r = 0; r < 4; r++) smPart[w][mt * 16 + g * 4 + r] = p[mt][r];
        }
        __syncthreads();
        if (t < 64) out[e0 + t] = smPart[0][t] + smPart[1][t] + smPart[2][t] + smPart[3][t] + b3v;
    }
}

extern "C" void kernel_launch(void* const* d_in, const int* in_sizes, int n_in,
                              void* d_out, int out_size, void* d_ws, size_t ws_size,
                              hipStream_t stream) {
    const float* x = (const float*)d_in[0];
    const int* ei = (const int*)d_in[1];
    const float* enc_W = (const float*)d_in[2];
    const float* enc_b = (const float*)d_in[3];
    const float* Wl = (const float*)d_in[4];
    const float* bl = (const float*)d_in[5];
    const float* Wr = (const float*)d_in[6];
    const float* br = (const float*)d_in[7];
    const float* att = (const float*)d_in[8];
    const float* gbias = (const float*)d_in[9];
    const float* c1_W = (const float*)d_in[10];
    const float* c1_b = (const float*)d_in[11];
    const float* c2_W = (const float*)d_in[12];
    const float* c2_b = (const float*)d_in[13];
    const float* c3_W = (const float*)d_in[14];
    const float* c3_b = (const float*)d_in[15];
    float* out = (float*)d_out;

    float* h = (float*)d_ws;
    float* xl = h + (size_t)N_NODES * DIM;
    float* xr = xl + (size_t)N_NODES * DIM;
    int* csr_src = (int*)(xr + (size_t)N_NODES * DIM);
    int* indptr = csr_src + N_EDGES;
    int* counts = indptr + (N_NODES + 1);
    int* bsum = counts + N_NODES;
    int* boff = bsum + 256;

    const int* srcp = ei;
    const int* dstp = ei + N_EDGES;
    const int NB = (N_NODES + 255) / 256;  // 196

    // CSR build
    zero_kernel<<<(N_NODES + 255) / 256, 256, 0, stream>>>(counts, N_NODES);
    hist_kernel<<<N_EDGES / 256, 256, 0, stream>>>(dstp, counts);
    scan1_kernel<<<NB, 256, 0, stream>>>(counts, indptr, bsum, N_NODES);
    scan2_kernel<<<1, 256, 0, stream>>>(bsum, boff, indptr, NB);
    scan3_kernel<<<NB, 256, 0, stream>>>(indptr, boff, N_NODES);
    zero_kernel<<<(N_NODES + 255) / 256, 256, 0, stream>>>(counts, N_NODES);
    place_kernel<<<N_EDGES / 256, 256, 0, stream>>>(srcp, dstp, indptr, counts, csr_src);

    // encoder
    encoder_kernel<<<(N_NODES * DIM) / 256, 256, 0, stream>>>(x, enc_W, enc_b, h);

    // GAT layers (fp32 xl/xr)
    for (int i = 0; i < NLAYER; i++) {
        transform_kernel<false><<<(N_NODES + 63) / 64, 256, 0, stream>>>(
            h, Wl + (size_t)i * DIM * DIM, bl + (size_t)i * DIM,
            Wr + (size_t)i * DIM * DIM, br + (size_t)i * DIM, xl, xr);
        gat_edge_kernel<<<N_NODES, 128, 0, stream>>>(xl, xr, att + (size_t)i * DIM,
                                                     gbias + (size_t)i * DIM, indptr, csr_src, h);
    }

    // classifier layer-1 node-level split: g1 = h@W1a + b1, g2 = h@W1b (bf16 storage; reuse xl/xr)
    transform_kernel<true><<<(N_NODES + 63) / 64, 256, 0, stream>>>(
        h, c1_W, c1_b, c1_W + 128 * DIM, nullptr, xl, xr);

    // fused edge MLP (64-edge tiles, MFMA layer2)
    edge_mlp_kernel<<<1024, 256, 0, stream>>>((const unsigned*)xl, (const unsigned*)xr, x, ei,
                                              c1_W + 256 * DIM, c2_W, c2_b, c3_W, c3_b, out, N_EDGES / 64);
}

// Round 5
// 805.870 us; speedup vs baseline: 3.0770x; 1.2576x over previous
//
#include <hip/hip_runtime.h>
#include <hip/hip_bf16.h>

#define N_NODES 50000
#define N_EDGES 800000
#define DIM 128
#define NLAYER 3
#define NEG 0.2f

typedef __attribute__((ext_vector_type(8))) short short8;
typedef __attribute__((ext_vector_type(4))) float f32x4;

// ---------------- utility ----------------
__global__ __launch_bounds__(256) void zero_kernel(int* p, int n) {
    int i = blockIdx.x * 256 + threadIdx.x;
    if (i < n) p[i] = 0;
}

// ---------------- CSR build ----------------
__global__ __launch_bounds__(256) void hist_kernel(const int* __restrict__ dst, int* __restrict__ counts) {
    int e = blockIdx.x * 256 + threadIdx.x;
    if (e < N_EDGES) atomicAdd(&counts[dst[e]], 1);
}

__global__ __launch_bounds__(256) void scan1_kernel(const int* __restrict__ counts, int* __restrict__ indptr,
                                                    int* __restrict__ bsum, int n) {
    __shared__ int buf[256];
    int t = threadIdx.x;
    int i = blockIdx.x * 256 + t;
    int v = (i < n) ? counts[i] : 0;
    buf[t] = v;
    __syncthreads();
    for (int off = 1; off < 256; off <<= 1) {
        int add = (t >= off) ? buf[t - off] : 0;
        __syncthreads();
        buf[t] += add;
        __syncthreads();
    }
    if (i < n) indptr[i + 1] = buf[t];
    if (t == 255) bsum[blockIdx.x] = buf[255];
}

__global__ __launch_bounds__(256) void scan2_kernel(int* __restrict__ bsum, int* __restrict__ boff,
                                                    int* __restrict__ indptr, int nb) {
    __shared__ int buf[256];
    int t = threadIdx.x;
    int v = (t < nb) ? bsum[t] : 0;
    buf[t] = v;
    __syncthreads();
    for (int off = 1; off < 256; off <<= 1) {
        int add = (t >= off) ? buf[t - off] : 0;
        __syncthreads();
        buf[t] += add;
        __syncthreads();
    }
    if (t < nb) boff[t] = buf[t] - v;  // exclusive
    if (t == 0) indptr[0] = 0;
}

__global__ __launch_bounds__(256) void scan3_kernel(int* __restrict__ indptr, const int* __restrict__ boff, int n) {
    int i = blockIdx.x * 256 + threadIdx.x;
    if (i < n) indptr[i + 1] += boff[i >> 8];
}

__global__ __launch_bounds__(256) void place_kernel(const int* __restrict__ srcp, const int* __restrict__ dstp,
                                                    const int* __restrict__ indptr, int* __restrict__ cursor,
                                                    int* __restrict__ csr_src) {
    int e = blockIdx.x * 256 + threadIdx.x;
    if (e < N_EDGES) {
        int dn = dstp[e];
        int pos = indptr[dn] + atomicAdd(&cursor[dn], 1);
        csr_src[pos] = srcp[e];
    }
}

// ---------------- encoder: h = relu(x @ enc_W + enc_b) ----------------
__global__ __launch_bounds__(256) void encoder_kernel(const float* __restrict__ x, const float* __restrict__ W,
                                                      const float* __restrict__ b, float* __restrict__ h) {
    int gid = blockIdx.x * 256 + threadIdx.x;
    int n = gid >> 7, d = gid & 127;
    if (n >= N_NODES) return;
    float acc = b[d];
#pragma unroll
    for (int f = 0; f < 5; f++) acc += x[n * 5 + f] * W[f * DIM + d];
    h[n * DIM + d] = fmaxf(acc, 0.f);
}

// ---------------- weight prep: split W into bf16 hi/lo, transposed [n][k] ----------------
// 8 matrices: {Wl[0],Wr[0],Wl[1],Wr[1],Wl[2],Wr[2],c1W_a,c1W_b}; each -> hi[16384] then lo[16384]
__global__ __launch_bounds__(256) void prep_weights_kernel(const float* __restrict__ Wl, const float* __restrict__ Wr,
                                                           const float* __restrict__ c1W,
                                                           unsigned short* __restrict__ wt) {
    int idx = blockIdx.x * 256 + threadIdx.x;  // 8 * 16384
    int m = idx >> 14;
    int r = idx & 16383;
    int n = r >> 7, k = r & 127;
    int L = m >> 1, half = m & 1;
    const float* W;
    if (L < 3) W = (half ? Wr : Wl) + (size_t)L * 16384;
    else W = c1W + (size_t)half * 16384;
    float v = W[k * 128 + n];
    __hip_bfloat16 hb = __float2bfloat16(v);
    float rl = v - __bfloat162float(hb);
    __hip_bfloat16 lb = __float2bfloat16(rl);
    wt[(size_t)m * 32768 + n * 128 + k] = *reinterpret_cast<unsigned short*>(&hb);
    wt[(size_t)m * 32768 + 16384 + n * 128 + k] = *reinterpret_cast<unsigned short*>(&lb);
}

// ---------------- dual GEMM via split-bf16 MFMA: outA = h@WA (+bA), outB = h@WB (+bB) ----------------
// h split into bf16 hi+lo in swizzled LDS; W fragments (pre-transposed bf16 hi/lo) read from global (L2).
// h@W = h_hi@W_hi + h_hi@W_lo + h_lo@W_hi  (error ~2^-18 rel)
template <bool BF16OUT>
__global__ __launch_bounds__(256) void transform_mfma_kernel(const float* __restrict__ h,
                                                             const unsigned short* __restrict__ wtA,
                                                             const float* __restrict__ bA,
                                                             const unsigned short* __restrict__ wtB,
                                                             const float* __restrict__ bB,
                                                             void* __restrict__ outA_, void* __restrict__ outB_) {
    __shared__ __align__(16) char hhi[64 * 256];  // bf16 [64][128], XOR-swizzled 16B rows
    __shared__ __align__(16) char hlo[64 * 256];
    int t = threadIdx.x;
    int l = t & 63, w = t >> 6;
    int n0 = blockIdx.x * 64;
    // stage + split h tile
    for (int i = t; i < 64 * 32; i += 256) {
        int row = i >> 5, c4 = (i & 31) * 4;
        int n = n0 + row;
        float4 v = make_float4(0.f, 0.f, 0.f, 0.f);
        if (n < N_NODES) v = *(const float4*)&h[(size_t)n * DIM + c4];
        const float* pv = &v.x;
        unsigned short hi4[4], lo4[4];
#pragma unroll
        for (int q = 0; q < 4; q++) {
            __hip_bfloat16 hb = __float2bfloat16(pv[q]);
            float rl = pv[q] - __bfloat162float(hb);
            __hip_bfloat16 lb = __float2bfloat16(rl);
            hi4[q] = *reinterpret_cast<unsigned short*>(&hb);
            lo4[q] = *reinterpret_cast<unsigned short*>(&lb);
        }
        int addr = (row * 256 + c4 * 2) ^ ((row & 7) << 4);
        *(ushort4*)(hhi + addr) = make_ushort4(hi4[0], hi4[1], hi4[2], hi4[3]);
        *(ushort4*)(hlo + addr) = make_ushort4(lo4[0], lo4[1], lo4[2], lo4[3]);
    }
    __syncthreads();

    int lane_m = l & 15, lane_k8 = l >> 4;
    int arow = w * 16 + lane_m;
    int aswz = (arow & 7) << 4;

#pragma unroll
    for (int mat = 0; mat < 2; mat++) {
        const short* wthi = (const short*)(mat ? wtB : wtA);
        const short* wtlo = wthi + 16384;
        const float* bias = mat ? bB : bA;
        f32x4 acc[8];
#pragma unroll
        for (int nt = 0; nt < 8; nt++) acc[nt] = (f32x4){0.f, 0.f, 0.f, 0.f};
#pragma unroll
        for (int ks = 0; ks < 4; ks++) {
            int kb = ks * 64 + lane_k8 * 16;  // byte offset in LDS row
            short8 ahi = *(const short8*)(hhi + ((arow * 256 + kb) ^ aswz));
            short8 alo = *(const short8*)(hlo + ((arow * 256 + kb) ^ aswz));
            int ke = ks * 32 + lane_k8 * 8;  // element offset in wt row
#pragma unroll
            for (int nt = 0; nt < 8; nt++) {
                int nrow = nt * 16 + lane_m;
                short8 bhi = *(const short8*)(wthi + nrow * 128 + ke);
                short8 blo = *(const short8*)(wtlo + nrow * 128 + ke);
                acc[nt] = __builtin_amdgcn_mfma_f32_16x16x32_bf16(ahi, bhi, acc[nt], 0, 0, 0);
                acc[nt] = __builtin_amdgcn_mfma_f32_16x16x32_bf16(ahi, blo, acc[nt], 0, 0, 0);
                acc[nt] = __builtin_amdgcn_mfma_f32_16x16x32_bf16(alo, bhi, acc[nt], 0, 0, 0);
            }
        }
        // epilogue: D row=(l>>4)*4+r (m), col=l&15 (n)
        void* outp = mat ? outB_ : outA_;
#pragma unroll
        for (int nt = 0; nt < 8; nt++) {
            int col = nt * 16 + lane_m;
            float bv = bias ? bias[col] : 0.f;
#pragma unroll
            for (int r = 0; r < 4; r++) {
                int node = n0 + w * 16 + lane_k8 * 4 + r;
                if (node < N_NODES) {
                    float v = acc[nt][r] + bv;
                    if constexpr (BF16OUT) {
                        ((__hip_bfloat16*)outp)[(size_t)node * DIM + col] = __float2bfloat16(v);
                    } else {
                        ((float*)outp)[(size_t)node * DIM + col] = v;
                    }
                }
            }
        }
    }
}

// ---------------- GATv2 edge+aggregate: self-loop seed, 4-way ILP online softmax ----------------
__device__ __forceinline__ float head_reduce(float a) {
    a += __shfl_xor(a, 16);
    a += __shfl_xor(a, 8);
    a += __shfl_xor(a, 4);
    a += __shfl_xor(a, 2);
    a += __shfl_xor(a, 1);
    return a;
}

__global__ __launch_bounds__(128) void gat_edge_kernel(const float* __restrict__ xl, const float* __restrict__ xr,
                                                       const float* __restrict__ att, const float* __restrict__ gbias,
                                                       const int* __restrict__ indptr, const int* __restrict__ csr_src,
                                                       float* __restrict__ h_out) {
    int n = blockIdx.x;
    int t = threadIdx.x;  // t = head*32 + c
    float xrv = xr[n * DIM + t];
    float attv = att[t];
    int beg = indptr[n], end = indptr[n + 1];

    float xls = xl[n * DIM + t];
    float es = xls + xrv;
    es = (es > 0.f) ? es : NEG * es;
    float m[4], den[4], acc[4];
    m[0] = head_reduce(es * attv); den[0] = 1.f; acc[0] = xls;
#pragma unroll
    for (int c = 1; c < 4; c++) { m[c] = -3.4e38f; den[c] = 0.f; acc[c] = 0.f; }

    int i = beg;
    for (; i + 4 <= end; i += 4) {
        int s[4];
        float v[4], a[4];
#pragma unroll
        for (int c = 0; c < 4; c++) s[c] = csr_src[i + c];
#pragma unroll
        for (int c = 0; c < 4; c++) v[c] = xl[s[c] * DIM + t];
#pragma unroll
        for (int c = 0; c < 4; c++) {
            float e = v[c] + xrv;
            e = (e > 0.f) ? e : NEG * e;
            a[c] = e * attv;
        }
#pragma unroll
        for (int off = 16; off >= 1; off >>= 1)
#pragma unroll
            for (int c = 0; c < 4; c++) a[c] += __shfl_xor(a[c], off);
#pragma unroll
        for (int c = 0; c < 4; c++) {
            float mn = fmaxf(m[c], a[c]);
            float sc = __expf(m[c] - mn), p = __expf(a[c] - mn);
            den[c] = den[c] * sc + p;
            acc[c] = acc[c] * sc + p * v[c];
            m[c] = mn;
        }
    }
    for (; i < end; ++i) {
        int s0 = csr_src[i];
        float v0 = xl[s0 * DIM + t];
        float e0 = v0 + xrv;
        e0 = (e0 > 0.f) ? e0 : NEG * e0;
        float a0 = head_reduce(e0 * attv);
        float mn = fmaxf(m[0], a0);
        float sc = __expf(m[0] - mn), p = __expf(a0 - mn);
        den[0] = den[0] * sc + p;
        acc[0] = acc[0] * sc + p * v0;
        m[0] = mn;
    }
    float mm = fmaxf(fmaxf(m[0], m[1]), fmaxf(m[2], m[3]));
    float dd = 0.f, aa = 0.f;
#pragma unroll
    for (int c = 0; c < 4; c++) {
        float sc = __expf(m[c] - mm);
        dd += den[c] * sc;
        aa += acc[c] * sc;
    }
    float o = aa / (dd + 1e-16f);
    float v = o + gbias[t];
    h_out[n * DIM + t] = (v > 0.f) ? v : __expf(v) - 1.f;
}

// ---------------- edge MLP: bf16 MFMA layer2, 64-edge tiles ----------------
__global__ __launch_bounds__(256) void edge_mlp_kernel(const unsigned* __restrict__ g1u, const unsigned* __restrict__ g2u,
                                                       const float* __restrict__ x, const int* __restrict__ ei,
                                                       const float* __restrict__ W1tail,  // c1_W rows 256,257
                                                       const float* __restrict__ W2, const float* __restrict__ b2,
                                                       const float* __restrict__ W3, const float* __restrict__ b3,
                                                       float* __restrict__ out, int ntiles) {
    __shared__ __align__(16) char smO1[64 * 256];   // 64 edges x 128 bf16, XOR-swizzled 16B
    __shared__ __align__(16) char smW2T[64 * 256];  // W2^T: [n][k] bf16, XOR-swizzled 16B
    __shared__ float smCw[2][128];
    __shared__ float smPart[4][64];
    __shared__ int rowi[64], coli[64];
    __shared__ float sdt[64], sdi[64];
    int t = threadIdx.x;
    int l = t & 63, w = t >> 6;

    for (int idx = t; idx < 128 * 64; idx += 256) {
        int k = idx >> 6, n = idx & 63;
        __hip_bfloat16 bv = __float2bfloat16(W2[idx]);
        unsigned short us = *reinterpret_cast<unsigned short*>(&bv);
        int addr = (n * 256 + k * 2) ^ ((n & 7) << 4);
        *(unsigned short*)(smW2T + addr) = us;
    }
    if (t < 128) {
        smCw[0][t] = W1tail[t];
        smCw[1][t] = W1tail[128 + t];
    }
    float b3v = b3[0];
    float b2v = b2[w * 16 + (l & 15)];
    float w3v = W3[w * 16 + (l & 15)];
    int koff = (l >> 4) * 16;

    for (int tile = blockIdx.x; tile < ntiles; tile += gridDim.x) {
        int e0 = tile * 64;
        __syncthreads();
        if (t < 64) {
            int r = ei[e0 + t], c = ei[N_EDGES + e0 + t];
            rowi[t] = r; coli[t] = c;
            sdt[t] = fabsf(x[r * 5 + 4] - x[c * 5 + 4]);
            float dx = x[r * 5 + 1] - x[c * 5 + 1];
            float dy = x[r * 5 + 2] - x[c * 5 + 2];
            float dz = x[r * 5 + 3] - x[c * 5 + 3];
            sdi[t] = sqrtf(dx * dx + dy * dy + dz * dz);
        }
        __syncthreads();
        for (int idx = t; idx < 64 * 16; idx += 256) {
            int e = idx >> 4, s4 = idx & 15;
            const uint4* p1 = (const uint4*)(g1u + rowi[e] * 64);
            const uint4* p2 = (const uint4*)(g2u + coli[e] * 64);
            uint4 u1 = p1[s4], u2 = p2[s4];
            float dtv = sdt[e], div = sdi[e];
            unsigned uo[4];
            const unsigned* a1 = &u1.x;
            const unsigned* a2 = &u2.x;
#pragma unroll
            for (int q = 0; q < 4; q++) {
                int d = s4 * 8 + q * 2;
                float lo = __uint_as_float(a1[q] << 16) + __uint_as_float(a2[q] << 16) + dtv * smCw[0][d] + div * smCw[1][d];
                float hi = __uint_as_float(a1[q] & 0xffff0000u) + __uint_as_float(a2[q] & 0xffff0000u) +
                           dtv * smCw[0][d + 1] + div * smCw[1][d + 1];
                lo = fmaxf(lo, 0.f); hi = fmaxf(hi, 0.f);
                __hip_bfloat16 blo = __float2bfloat16(lo), bhi = __float2bfloat16(hi);
                unsigned short ulo = *reinterpret_cast<unsigned short*>(&blo);
                unsigned short uhi = *reinterpret_cast<unsigned short*>(&bhi);
                uo[q] = (unsigned)ulo | ((unsigned)uhi << 16);
            }
            int addr = (e * 256 + s4 * 16) ^ ((e & 7) << 4);
            *(uint4*)(smO1 + addr) = *(uint4*)uo;
        }
        __syncthreads();
        f32x4 acc[4];
#pragma unroll
        for (int mt = 0; mt < 4; mt++) acc[mt] = (f32x4){0.f, 0.f, 0.f, 0.f};
        int nrow = w * 16 + (l & 15);
#pragma unroll
        for (int ks = 0; ks < 4; ks++) {
            short8 bfrag = *(const short8*)(smW2T + ((nrow * 256 + koff + ks * 64) ^ ((nrow & 7) << 4)));
#pragma unroll
            for (int mt = 0; mt < 4; mt++) {
                int mrow = mt * 16 + (l & 15);
                short8 afrag = *(const short8*)(smO1 + ((mrow * 256 + koff + ks * 64) ^ ((mrow & 7) << 4)));
                acc[mt] = __builtin_amdgcn_mfma_f32_16x16x32_bf16(afrag, bfrag, acc[mt], 0, 0, 0);
            }
        }
        float p[4][4];
#pragma unroll
        for (int mt = 0; mt < 4; mt++)
#pragma unroll
            for (int r = 0; r < 4; r++) p[mt][r] = fmaxf(acc[mt][r] + b2v, 0.f) * w3v;
#pragma unroll
        for (int off = 8; off >= 1; off >>= 1)
#pragma unroll
            for (int mt = 0; mt < 4; mt++)
#pragma unroll
                for (int r = 0; r < 4; r++) p[mt][r] += __shfl_xor(p[mt][r], off);
        if ((l & 15) == 0) {
            int g = l >> 4;
#pragma unroll
            for (int mt = 0; mt < 4; mt++)
#pragma unroll
                for (int r = 0; r < 4; r++) smPart[w][mt * 16 + g * 4 + r] = p[mt][r];
        }
        __syncthreads();
        if (t < 64) out[e0 + t] = smPart[0][t] + smPart[1][t] + smPart[2][t] + smPart[3][t] + b3v;
    }
}

extern "C" void kernel_launch(void* const* d_in, const int* in_sizes, int n_in,
                              void* d_out, int out_size, void* d_ws, size_t ws_size,
                              hipStream_t stream) {
    const float* x = (const float*)d_in[0];
    const int* ei = (const int*)d_in[1];
    const float* enc_W = (const float*)d_in[2];
    const float* enc_b = (const float*)d_in[3];
    const float* Wl = (const float*)d_in[4];
    const float* bl = (const float*)d_in[5];
    const float* Wr = (const float*)d_in[6];
    const float* br = (const float*)d_in[7];
    const float* att = (const float*)d_in[8];
    const float* gbias = (const float*)d_in[9];
    const float* c1_W = (const float*)d_in[10];
    const float* c1_b = (const float*)d_in[11];
    const float* c2_W = (const float*)d_in[12];
    const float* c2_b = (const float*)d_in[13];
    const float* c3_W = (const float*)d_in[14];
    const float* c3_b = (const float*)d_in[15];
    float* out = (float*)d_out;

    float* h = (float*)d_ws;
    float* xl = h + (size_t)N_NODES * DIM;
    float* xr = xl + (size_t)N_NODES * DIM;
    int* csr_src = (int*)(xr + (size_t)N_NODES * DIM);
    int* indptr = csr_src + N_EDGES;
    int* counts = indptr + (N_NODES + 1);
    int* bsum = counts + N_NODES;
    int* boff = bsum + 256;
    uintptr_t wp = (uintptr_t)(boff + 256);
    wp = (wp + 15) & ~(uintptr_t)15;
    unsigned short* wt = (unsigned short*)wp;  // 8 matrices x {hi,lo} x 16384 bf16 = 512 KB

    const int* srcp = ei;
    const int* dstp = ei + N_EDGES;
    const int NB = (N_NODES + 255) / 256;  // 196
    const int TGRID = (N_NODES + 63) / 64;  // 782

    // weight prep (transpose + hi/lo split)
    prep_weights_kernel<<<8 * 16384 / 256, 256, 0, stream>>>(Wl, Wr, c1_W, wt);

    // CSR build
    zero_kernel<<<(N_NODES + 255) / 256, 256, 0, stream>>>(counts, N_NODES);
    hist_kernel<<<N_EDGES / 256, 256, 0, stream>>>(dstp, counts);
    scan1_kernel<<<NB, 256, 0, stream>>>(counts, indptr, bsum, N_NODES);
    scan2_kernel<<<1, 256, 0, stream>>>(bsum, boff, indptr, NB);
    scan3_kernel<<<NB, 256, 0, stream>>>(indptr, boff, N_NODES);
    zero_kernel<<<(N_NODES + 255) / 256, 256, 0, stream>>>(counts, N_NODES);
    place_kernel<<<N_EDGES / 256, 256, 0, stream>>>(srcp, dstp, indptr, counts, csr_src);

    // encoder
    encoder_kernel<<<(N_NODES * DIM) / 256, 256, 0, stream>>>(x, enc_W, enc_b, h);

    // GAT layers (split-bf16 MFMA transforms, fp32 xl/xr outputs)
    for (int i = 0; i < NLAYER; i++) {
        transform_mfma_kernel<false><<<TGRID, 256, 0, stream>>>(
            h, wt + (size_t)(i * 2) * 32768, bl + (size_t)i * DIM,
            wt + (size_t)(i * 2 + 1) * 32768, br + (size_t)i * DIM, xl, xr);
        gat_edge_kernel<<<N_NODES, 128, 0, stream>>>(xl, xr, att + (size_t)i * DIM,
                                                     gbias + (size_t)i * DIM, indptr, csr_src, h);
    }

    // classifier layer-1 node-level split: g1 = h@W1a + b1, g2 = h@W1b (bf16 storage; reuse xl/xr)
    transform_mfma_kernel<true><<<TGRID, 256, 0, stream>>>(
        h, wt + (size_t)(6) * 32768, c1_b, wt + (size_t)(7) * 32768, nullptr, xl, xr);

    // fused edge MLP (64-edge tiles, MFMA layer2)
    edge_mlp_kernel<<<1024, 256, 0, stream>>>((const unsigned*)xl, (const unsigned*)xr, x, ei,
                                              c1_W + 256 * DIM, c2_W, c2_b, c3_W, c3_b, out, N_EDGES / 64);
}

// Round 6
// 736.295 us; speedup vs baseline: 3.3678x; 1.0945x over previous
//
#include <hip/hip_runtime.h>
#include <hip/hip_bf16.h>

#define N_NODES 50000
#define N_EDGES 800000
#define DIM 128
#define NLAYER 3
#define NEG 0.2f

typedef __attribute__((ext_vector_type(8))) short short8;
typedef __attribute__((ext_vector_type(4))) float f32x4;

// ---------------- utility ----------------
__global__ __launch_bounds__(256) void zero_kernel(int* p, int n) {
    int i = blockIdx.x * 256 + threadIdx.x;
    if (i < n) p[i] = 0;
}

// ---------------- CSR build ----------------
__global__ __launch_bounds__(256) void hist_kernel(const int* __restrict__ dst, int* __restrict__ counts) {
    int e = blockIdx.x * 256 + threadIdx.x;
    if (e < N_EDGES) atomicAdd(&counts[dst[e]], 1);
}

__global__ __launch_bounds__(256) void scan1_kernel(const int* __restrict__ counts, int* __restrict__ indptr,
                                                    int* __restrict__ bsum, int n) {
    __shared__ int buf[256];
    int t = threadIdx.x;
    int i = blockIdx.x * 256 + t;
    int v = (i < n) ? counts[i] : 0;
    buf[t] = v;
    __syncthreads();
    for (int off = 1; off < 256; off <<= 1) {
        int add = (t >= off) ? buf[t - off] : 0;
        __syncthreads();
        buf[t] += add;
        __syncthreads();
    }
    if (i < n) indptr[i + 1] = buf[t];
    if (t == 255) bsum[blockIdx.x] = buf[255];
}

__global__ __launch_bounds__(256) void scan2_kernel(int* __restrict__ bsum, int* __restrict__ boff,
                                                    int* __restrict__ indptr, int nb) {
    __shared__ int buf[256];
    int t = threadIdx.x;
    int v = (t < nb) ? bsum[t] : 0;
    buf[t] = v;
    __syncthreads();
    for (int off = 1; off < 256; off <<= 1) {
        int add = (t >= off) ? buf[t - off] : 0;
        __syncthreads();
        buf[t] += add;
        __syncthreads();
    }
    if (t < nb) boff[t] = buf[t] - v;  // exclusive
    if (t == 0) indptr[0] = 0;
}

__global__ __launch_bounds__(256) void scan3_kernel(int* __restrict__ indptr, const int* __restrict__ boff, int n) {
    int i = blockIdx.x * 256 + threadIdx.x;
    if (i < n) indptr[i + 1] += boff[i >> 8];
}

__global__ __launch_bounds__(256) void place_kernel(const int* __restrict__ srcp, const int* __restrict__ dstp,
                                                    const int* __restrict__ indptr, int* __restrict__ cursor,
                                                    int* __restrict__ csr_src) {
    int e = blockIdx.x * 256 + threadIdx.x;
    if (e < N_EDGES) {
        int dn = dstp[e];
        int pos = indptr[dn] + atomicAdd(&cursor[dn], 1);
        csr_src[pos] = srcp[e];
    }
}

// ---------------- encoder: h = relu(x @ enc_W + enc_b) ----------------
__global__ __launch_bounds__(256) void encoder_kernel(const float* __restrict__ x, const float* __restrict__ W,
                                                      const float* __restrict__ b, float* __restrict__ h) {
    int gid = blockIdx.x * 256 + threadIdx.x;
    int n = gid >> 7, d = gid & 127;
    if (n >= N_NODES) return;
    float acc = b[d];
#pragma unroll
    for (int f = 0; f < 5; f++) acc += x[n * 5 + f] * W[f * DIM + d];
    h[n * DIM + d] = fmaxf(acc, 0.f);
}

// ---------------- weight prep: split W into bf16 hi/lo, transposed [n][k] ----------------
__global__ __launch_bounds__(256) void prep_weights_kernel(const float* __restrict__ Wl, const float* __restrict__ Wr,
                                                           const float* __restrict__ c1W,
                                                           unsigned short* __restrict__ wt) {
    int idx = blockIdx.x * 256 + threadIdx.x;  // 8 * 16384
    int m = idx >> 14;
    int r = idx & 16383;
    int n = r >> 7, k = r & 127;
    int L = m >> 1, half = m & 1;
    const float* W;
    if (L < 3) W = (half ? Wr : Wl) + (size_t)L * 16384;
    else W = c1W + (size_t)half * 16384;
    float v = W[k * 128 + n];
    __hip_bfloat16 hb = __float2bfloat16(v);
    float rl = v - __bfloat162float(hb);
    __hip_bfloat16 lb = __float2bfloat16(rl);
    wt[(size_t)m * 32768 + n * 128 + k] = *reinterpret_cast<unsigned short*>(&hb);
    wt[(size_t)m * 32768 + 16384 + n * 128 + k] = *reinterpret_cast<unsigned short*>(&lb);
}

// ---------------- dual GEMM via split-bf16 MFMA ----------------
template <bool BF16OUT>
__global__ __launch_bounds__(256) void transform_mfma_kernel(const float* __restrict__ h,
                                                             const unsigned short* __restrict__ wtA,
                                                             const float* __restrict__ bA,
                                                             const unsigned short* __restrict__ wtB,
                                                             const float* __restrict__ bB,
                                                             void* __restrict__ outA_, void* __restrict__ outB_) {
    __shared__ __align__(16) char hhi[64 * 256];  // bf16 [64][128], XOR-swizzled 16B rows
    __shared__ __align__(16) char hlo[64 * 256];
    int t = threadIdx.x;
    int l = t & 63, w = t >> 6;
    int n0 = blockIdx.x * 64;
    for (int i = t; i < 64 * 32; i += 256) {
        int row = i >> 5, c4 = (i & 31) * 4;
        int n = n0 + row;
        float4 v = make_float4(0.f, 0.f, 0.f, 0.f);
        if (n < N_NODES) v = *(const float4*)&h[(size_t)n * DIM + c4];
        const float* pv = &v.x;
        unsigned short hi4[4], lo4[4];
#pragma unroll
        for (int q = 0; q < 4; q++) {
            __hip_bfloat16 hb = __float2bfloat16(pv[q]);
            float rl = pv[q] - __bfloat162float(hb);
            __hip_bfloat16 lb = __float2bfloat16(rl);
            hi4[q] = *reinterpret_cast<unsigned short*>(&hb);
            lo4[q] = *reinterpret_cast<unsigned short*>(&lb);
        }
        int addr = (row * 256 + c4 * 2) ^ ((row & 7) << 4);
        *(ushort4*)(hhi + addr) = make_ushort4(hi4[0], hi4[1], hi4[2], hi4[3]);
        *(ushort4*)(hlo + addr) = make_ushort4(lo4[0], lo4[1], lo4[2], lo4[3]);
    }
    __syncthreads();

    int lane_m = l & 15, lane_k8 = l >> 4;
    int arow = w * 16 + lane_m;
    int aswz = (arow & 7) << 4;

#pragma unroll
    for (int mat = 0; mat < 2; mat++) {
        const short* wthi = (const short*)(mat ? wtB : wtA);
        const short* wtlo = wthi + 16384;
        const float* bias = mat ? bB : bA;
        f32x4 acc[8];
#pragma unroll
        for (int nt = 0; nt < 8; nt++) acc[nt] = (f32x4){0.f, 0.f, 0.f, 0.f};
#pragma unroll
        for (int ks = 0; ks < 4; ks++) {
            int kb = ks * 64 + lane_k8 * 16;
            short8 ahi = *(const short8*)(hhi + ((arow * 256 + kb) ^ aswz));
            short8 alo = *(const short8*)(hlo + ((arow * 256 + kb) ^ aswz));
            int ke = ks * 32 + lane_k8 * 8;
#pragma unroll
            for (int nt = 0; nt < 8; nt++) {
                int nrow = nt * 16 + lane_m;
                short8 bhi = *(const short8*)(wthi + nrow * 128 + ke);
                short8 blo = *(const short8*)(wtlo + nrow * 128 + ke);
                acc[nt] = __builtin_amdgcn_mfma_f32_16x16x32_bf16(ahi, bhi, acc[nt], 0, 0, 0);
                acc[nt] = __builtin_amdgcn_mfma_f32_16x16x32_bf16(ahi, blo, acc[nt], 0, 0, 0);
                acc[nt] = __builtin_amdgcn_mfma_f32_16x16x32_bf16(alo, bhi, acc[nt], 0, 0, 0);
            }
        }
        void* outp = mat ? outB_ : outA_;
#pragma unroll
        for (int nt = 0; nt < 8; nt++) {
            int col = nt * 16 + lane_m;
            float bv = bias ? bias[col] : 0.f;
#pragma unroll
            for (int r = 0; r < 4; r++) {
                int node = n0 + w * 16 + lane_k8 * 4 + r;
                if (node < N_NODES) {
                    float v = acc[nt][r] + bv;
                    if constexpr (BF16OUT) {
                        ((__hip_bfloat16*)outp)[(size_t)node * DIM + col] = __float2bfloat16(v);
                    } else {
                        ((float*)outp)[(size_t)node * DIM + col] = v;
                    }
                }
            }
        }
    }
}

// ---------------- GATv2 edge+aggregate v3: wave-per-node, float4 lanes, 4 edges/iter ----------------
// lane l: half = l>>5 (edge slot), sl = l&31, channels 4*sl..4*sl+3 (head = sl>>3, 8-lane groups)
__device__ __forceinline__ float edge_score(float4 v, float4 xrv, float4 attv) {
    float z, a;
    z = v.x + xrv.x; z = fmaxf(z, NEG * z); a = z * attv.x;
    z = v.y + xrv.y; z = fmaxf(z, NEG * z); a += z * attv.y;
    z = v.z + xrv.z; z = fmaxf(z, NEG * z); a += z * attv.z;
    z = v.w + xrv.w; z = fmaxf(z, NEG * z); a += z * attv.w;
    a += __shfl_xor(a, 1);
    a += __shfl_xor(a, 2);
    a += __shfl_xor(a, 4);
    return a;
}

__global__ __launch_bounds__(256) void gat_edge_kernel(const float* __restrict__ xl, const float* __restrict__ xr,
                                                       const float* __restrict__ att, const float* __restrict__ gbias,
                                                       const int* __restrict__ indptr, const int* __restrict__ csr_src,
                                                       float* __restrict__ h_out) {
    int n = blockIdx.x * 4 + (threadIdx.x >> 6);  // wave-per-node
    int l = threadIdx.x & 63;
    int half = l >> 5;
    int c0 = (l & 31) * 4;
    float4 xrv = *(const float4*)&xr[(size_t)n * DIM + c0];
    float4 attv = *(const float4*)&att[c0];
    int beg = indptr[n], end = indptr[n + 1];

    float m[2], den[2];
    float4 acc[2];
    // self-loop seeds chain 0 of half 0
    {
        float4 v = *(const float4*)&xl[(size_t)n * DIM + c0];
        float a = edge_score(v, xrv, attv);
        if (half == 0) {
            m[0] = a; den[0] = 1.f; acc[0] = v;
        } else {
            m[0] = -3.4e38f; den[0] = 0.f; acc[0] = make_float4(0.f, 0.f, 0.f, 0.f);
        }
        m[1] = -3.4e38f; den[1] = 0.f; acc[1] = make_float4(0.f, 0.f, 0.f, 0.f);
    }

    for (int i = beg; i < end; i += 4) {
#pragma unroll
        for (int c = 0; c < 2; c++) {
            int idx = i + 2 * c + half;
            bool valid = idx < end;
            int s = valid ? csr_src[idx] : n;
            float4 v = *(const float4*)&xl[(size_t)s * DIM + c0];
            float a = edge_score(v, xrv, attv);
            if (!valid) a = -3.4e38f;
            float mn = fmaxf(m[c], a);
            float sc = __expf(m[c] - mn), p = __expf(a - mn);
            den[c] = den[c] * sc + p;
            acc[c].x = acc[c].x * sc + p * v.x;
            acc[c].y = acc[c].y * sc + p * v.y;
            acc[c].z = acc[c].z * sc + p * v.z;
            acc[c].w = acc[c].w * sc + p * v.w;
            m[c] = mn;
        }
    }
    // merge chain 1 into chain 0 (lane-local)
    {
        float mm = fmaxf(m[0], m[1]);
        float s0 = __expf(m[0] - mm), s1 = __expf(m[1] - mm);
        den[0] = den[0] * s0 + den[1] * s1;
        acc[0].x = acc[0].x * s0 + acc[1].x * s1;
        acc[0].y = acc[0].y * s0 + acc[1].y * s1;
        acc[0].z = acc[0].z * s0 + acc[1].z * s1;
        acc[0].w = acc[0].w * s0 + acc[1].w * s1;
        m[0] = mm;
    }
    // merge across halves (lane l <-> l^32)
    {
        float mo = __shfl_xor(m[0], 32);
        float dno = __shfl_xor(den[0], 32);
        float4 ao;
        ao.x = __shfl_xor(acc[0].x, 32);
        ao.y = __shfl_xor(acc[0].y, 32);
        ao.z = __shfl_xor(acc[0].z, 32);
        ao.w = __shfl_xor(acc[0].w, 32);
        float mm = fmaxf(m[0], mo);
        float s0 = __expf(m[0] - mm), s1 = __expf(mo - mm);
        den[0] = den[0] * s0 + dno * s1;
        acc[0].x = acc[0].x * s0 + ao.x * s1;
        acc[0].y = acc[0].y * s0 + ao.y * s1;
        acc[0].z = acc[0].z * s0 + ao.z * s1;
        acc[0].w = acc[0].w * s0 + ao.w * s1;
    }
    if (half == 0) {
        float4 gb = *(const float4*)&gbias[c0];
        float inv = 1.f / (den[0] + 1e-16f);
        float4 o;
        o.x = acc[0].x * inv + gb.x;
        o.y = acc[0].y * inv + gb.y;
        o.z = acc[0].z * inv + gb.z;
        o.w = acc[0].w * inv + gb.w;
        o.x = (o.x > 0.f) ? o.x : __expf(o.x) - 1.f;
        o.y = (o.y > 0.f) ? o.y : __expf(o.y) - 1.f;
        o.z = (o.z > 0.f) ? o.z : __expf(o.z) - 1.f;
        o.w = (o.w > 0.f) ? o.w : __expf(o.w) - 1.f;
        *(float4*)&h_out[(size_t)n * DIM + c0] = o;
    }
}

// ---------------- edge MLP: bf16 MFMA layer2, 64-edge tiles ----------------
__global__ __launch_bounds__(256) void edge_mlp_kernel(const unsigned* __restrict__ g1u, const unsigned* __restrict__ g2u,
                                                       const float* __restrict__ x, const int* __restrict__ ei,
                                                       const float* __restrict__ W1tail,  // c1_W rows 256,257
                                                       const float* __restrict__ W2, const float* __restrict__ b2,
                                                       const float* __restrict__ W3, const float* __restrict__ b3,
                                                       float* __restrict__ out, int ntiles) {
    __shared__ __align__(16) char smO1[64 * 256];   // 64 edges x 128 bf16, XOR-swizzled 16B
    __shared__ __align__(16) char smW2T[64 * 256];  // W2^T: [n][k] bf16, XOR-swizzled 16B
    __shared__ float smCw[2][128];
    __shared__ float smPart[4][64];
    __shared__ int rowi[64], coli[64];
    __shared__ float sdt[64], sdi[64];
    int t = threadIdx.x;
    int l = t & 63, w = t >> 6;

    for (int idx = t; idx < 128 * 64; idx += 256) {
        int k = idx >> 6, n = idx & 63;
        __hip_bfloat16 bv = __float2bfloat16(W2[idx]);
        unsigned short us = *reinterpret_cast<unsigned short*>(&bv);
        int addr = (n * 256 + k * 2) ^ ((n & 7) << 4);
        *(unsigned short*)(smW2T + addr) = us;
    }
    if (t < 128) {
        smCw[0][t] = W1tail[t];
        smCw[1][t] = W1tail[128 + t];
    }
    float b3v = b3[0];
    float b2v = b2[w * 16 + (l & 15)];
    float w3v = W3[w * 16 + (l & 15)];
    int koff = (l >> 4) * 16;

    for (int tile = blockIdx.x; tile < ntiles; tile += gridDim.x) {
        int e0 = tile * 64;
        __syncthreads();
        if (t < 64) {
            int r = ei[e0 + t], c = ei[N_EDGES + e0 + t];
            rowi[t] = r; coli[t] = c;
            sdt[t] = fabsf(x[r * 5 + 4] - x[c * 5 + 4]);
            float dx = x[r * 5 + 1] - x[c * 5 + 1];
            float dy = x[r * 5 + 2] - x[c * 5 + 2];
            float dz = x[r * 5 + 3] - x[c * 5 + 3];
            sdi[t] = sqrtf(dx * dx + dy * dy + dz * dz);
        }
        __syncthreads();
        for (int idx = t; idx < 64 * 16; idx += 256) {
            int e = idx >> 4, s4 = idx & 15;
            const uint4* p1 = (const uint4*)(g1u + rowi[e] * 64);
            const uint4* p2 = (const uint4*)(g2u + coli[e] * 64);
            uint4 u1 = p1[s4], u2 = p2[s4];
            float dtv = sdt[e], div = sdi[e];
            unsigned uo[4];
            const unsigned* a1 = &u1.x;
            const unsigned* a2 = &u2.x;
#pragma unroll
            for (int q = 0; q < 4; q++) {
                int d = s4 * 8 + q * 2;
                float lo = __uint_as_float(a1[q] << 16) + __uint_as_float(a2[q] << 16) + dtv * smCw[0][d] + div * smCw[1][d];
                float hi = __uint_as_float(a1[q] & 0xffff0000u) + __uint_as_float(a2[q] & 0xffff0000u) +
                           dtv * smCw[0][d + 1] + div * smCw[1][d + 1];
                lo = fmaxf(lo, 0.f); hi = fmaxf(hi, 0.f);
                __hip_bfloat16 blo = __float2bfloat16(lo), bhi = __float2bfloat16(hi);
                unsigned short ulo = *reinterpret_cast<unsigned short*>(&blo);
                unsigned short uhi = *reinterpret_cast<unsigned short*>(&bhi);
                uo[q] = (unsigned)ulo | ((unsigned)uhi << 16);
            }
            int addr = (e * 256 + s4 * 16) ^ ((e & 7) << 4);
            *(uint4*)(smO1 + addr) = *(uint4*)uo;
        }
        __syncthreads();
        f32x4 acc[4];
#pragma unroll
        for (int mt = 0; mt < 4; mt++) acc[mt] = (f32x4){0.f, 0.f, 0.f, 0.f};
        int nrow = w * 16 + (l & 15);
#pragma unroll
        for (int ks = 0; ks < 4; ks++) {
            short8 bfrag = *(const short8*)(smW2T + ((nrow * 256 + koff + ks * 64) ^ ((nrow & 7) << 4)));
#pragma unroll
            for (int mt = 0; mt < 4; mt++) {
                int mrow = mt * 16 + (l & 15);
                short8 afrag = *(const short8*)(smO1 + ((mrow * 256 + koff + ks * 64) ^ ((mrow & 7) << 4)));
                acc[mt] = __builtin_amdgcn_mfma_f32_16x16x32_bf16(afrag, bfrag, acc[mt], 0, 0, 0);
            }
        }
        float p[4][4];
#pragma unroll
        for (int mt = 0; mt < 4; mt++)
#pragma unroll
            for (int r = 0; r < 4; r++) p[mt][r] = fmaxf(acc[mt][r] + b2v, 0.f) * w3v;
#pragma unroll
        for (int off = 8; off >= 1; off >>= 1)
#pragma unroll
            for (int mt = 0; mt < 4; mt++)
#pragma unroll
                for (int r = 0; r < 4; r++) p[mt][r] += __shfl_xor(p[mt][r], off);
        if ((l & 15) == 0) {
            int g = l >> 4;
#pragma unroll
            for (int mt = 0; mt < 4; mt++)
#pragma unroll
                for (int r = 0; r < 4; r++) smPart[w][mt * 16 + g * 4 + r] = p[mt][r];
        }
        __syncthreads();
        if (t < 64) out[e0 + t] = smPart[0][t] + smPart[1][t] + smPart[2][t] + smPart[3][t] + b3v;
    }
}

extern "C" void kernel_launch(void* const* d_in, const int* in_sizes, int n_in,
                              void* d_out, int out_size, void* d_ws, size_t ws_size,
                              hipStream_t stream) {
    const float* x = (const float*)d_in[0];
    const int* ei = (const int*)d_in[1];
    const float* enc_W = (const float*)d_in[2];
    const float* enc_b = (const float*)d_in[3];
    const float* Wl = (const float*)d_in[4];
    const float* bl = (const float*)d_in[5];
    const float* Wr = (const float*)d_in[6];
    const float* br = (const float*)d_in[7];
    const float* att = (const float*)d_in[8];
    const float* gbias = (const float*)d_in[9];
    const float* c1_W = (const float*)d_in[10];
    const float* c1_b = (const float*)d_in[11];
    const float* c2_W = (const float*)d_in[12];
    const float* c2_b = (const float*)d_in[13];
    const float* c3_W = (const float*)d_in[14];
    const float* c3_b = (const float*)d_in[15];
    float* out = (float*)d_out;

    float* h = (float*)d_ws;
    float* xl = h + (size_t)N_NODES * DIM;
    float* xr = xl + (size_t)N_NODES * DIM;
    int* csr_src = (int*)(xr + (size_t)N_NODES * DIM);
    int* indptr = csr_src + N_EDGES;
    int* counts = indptr + (N_NODES + 1);
    int* bsum = counts + N_NODES;
    int* boff = bsum + 256;
    uintptr_t wp = (uintptr_t)(boff + 256);
    wp = (wp + 15) & ~(uintptr_t)15;
    unsigned short* wt = (unsigned short*)wp;  // 8 matrices x {hi,lo} x 16384 bf16 = 512 KB

    const int* srcp = ei;
    const int* dstp = ei + N_EDGES;
    const int NB = (N_NODES + 255) / 256;  // 196
    const int TGRID = (N_NODES + 63) / 64;  // 782

    // weight prep (transpose + hi/lo split)
    prep_weights_kernel<<<8 * 16384 / 256, 256, 0, stream>>>(Wl, Wr, c1_W, wt);

    // CSR build
    zero_kernel<<<(N_NODES + 255) / 256, 256, 0, stream>>>(counts, N_NODES);
    hist_kernel<<<N_EDGES / 256, 256, 0, stream>>>(dstp, counts);
    scan1_kernel<<<NB, 256, 0, stream>>>(counts, indptr, bsum, N_NODES);
    scan2_kernel<<<1, 256, 0, stream>>>(bsum, boff, indptr, NB);
    scan3_kernel<<<NB, 256, 0, stream>>>(indptr, boff, N_NODES);
    zero_kernel<<<(N_NODES + 255) / 256, 256, 0, stream>>>(counts, N_NODES);
    place_kernel<<<N_EDGES / 256, 256, 0, stream>>>(srcp, dstp, indptr, counts, csr_src);

    // encoder
    encoder_kernel<<<(N_NODES * DIM) / 256, 256, 0, stream>>>(x, enc_W, enc_b, h);

    // GAT layers (split-bf16 MFMA transforms, fp32 xl/xr; wave-per-node edge kernel)
    for (int i = 0; i < NLAYER; i++) {
        transform_mfma_kernel<false><<<TGRID, 256, 0, stream>>>(
            h, wt + (size_t)(i * 2) * 32768, bl + (size_t)i * DIM,
            wt + (size_t)(i * 2 + 1) * 32768, br + (size_t)i * DIM, xl, xr);
        gat_edge_kernel<<<N_NODES / 4, 256, 0, stream>>>(xl, xr, att + (size_t)i * DIM,
                                                         gbias + (size_t)i * DIM, indptr, csr_src, h);
    }

    // classifier layer-1 node-level split: g1 = h@W1a + b1, g2 = h@W1b (bf16 storage; reuse xl/xr)
    transform_mfma_kernel<true><<<TGRID, 256, 0, stream>>>(
        h, wt + (size_t)6 * 32768, c1_b, wt + (size_t)7 * 32768, nullptr, xl, xr);

    // fused edge MLP (64-edge tiles, MFMA layer2)
    edge_mlp_kernel<<<1024, 256, 0, stream>>>((const unsigned*)xl, (const unsigned*)xr, x, ei,
                                              c1_W + 256 * DIM, c2_W, c2_b, c3_W, c3_b, out, N_EDGES / 64);
}

// Round 7
// 596.300 us; speedup vs baseline: 4.1584x; 1.2348x over previous
//
#include <hip/hip_runtime.h>
#include <hip/hip_bf16.h>

#define N_NODES 50000
#define N_EDGES 800000
#define DIM 128
#define NLAYER 3
#define NEG 0.2f

typedef __attribute__((ext_vector_type(8))) short short8;
typedef __attribute__((ext_vector_type(4))) float f32x4;

// ---------------- utility ----------------
__global__ __launch_bounds__(256) void zero_kernel(int* p, int n) {
    int i = blockIdx.x * 256 + threadIdx.x;
    if (i < n) p[i] = 0;
}

// ---------------- CSR build ----------------
__global__ __launch_bounds__(256) void hist_kernel(const int* __restrict__ dst, int* __restrict__ counts) {
    int e = blockIdx.x * 256 + threadIdx.x;
    if (e < N_EDGES) atomicAdd(&counts[dst[e]], 1);
}

__global__ __launch_bounds__(256) void scan1_kernel(const int* __restrict__ counts, int* __restrict__ indptr,
                                                    int* __restrict__ bsum, int n) {
    __shared__ int buf[256];
    int t = threadIdx.x;
    int i = blockIdx.x * 256 + t;
    int v = (i < n) ? counts[i] : 0;
    buf[t] = v;
    __syncthreads();
    for (int off = 1; off < 256; off <<= 1) {
        int add = (t >= off) ? buf[t - off] : 0;
        __syncthreads();
        buf[t] += add;
        __syncthreads();
    }
    if (i < n) indptr[i + 1] = buf[t];
    if (t == 255) bsum[blockIdx.x] = buf[255];
}

__global__ __launch_bounds__(256) void scan2_kernel(int* __restrict__ bsum, int* __restrict__ boff,
                                                    int* __restrict__ indptr, int nb) {
    __shared__ int buf[256];
    int t = threadIdx.x;
    int v = (t < nb) ? bsum[t] : 0;
    buf[t] = v;
    __syncthreads();
    for (int off = 1; off < 256; off <<= 1) {
        int add = (t >= off) ? buf[t - off] : 0;
        __syncthreads();
        buf[t] += add;
        __syncthreads();
    }
    if (t < nb) boff[t] = buf[t] - v;  // exclusive
    if (t == 0) indptr[0] = 0;
}

__global__ __launch_bounds__(256) void scan3_kernel(int* __restrict__ indptr, const int* __restrict__ boff, int n) {
    int i = blockIdx.x * 256 + threadIdx.x;
    if (i < n) indptr[i + 1] += boff[i >> 8];
}

__global__ __launch_bounds__(256) void place_kernel(const int* __restrict__ srcp, const int* __restrict__ dstp,
                                                    const int* __restrict__ indptr, int* __restrict__ cursor,
                                                    int* __restrict__ csr_src) {
    int e = blockIdx.x * 256 + threadIdx.x;
    if (e < N_EDGES) {
        int dn = dstp[e];
        int pos = indptr[dn] + atomicAdd(&cursor[dn], 1);
        csr_src[pos] = srcp[e];
    }
}

// ---------------- encoder: h = relu(x @ enc_W + enc_b) ----------------
__global__ __launch_bounds__(256) void encoder_kernel(const float* __restrict__ x, const float* __restrict__ W,
                                                      const float* __restrict__ b, float* __restrict__ h) {
    int gid = blockIdx.x * 256 + threadIdx.x;
    int n = gid >> 7, d = gid & 127;
    if (n >= N_NODES) return;
    float acc = b[d];
#pragma unroll
    for (int f = 0; f < 5; f++) acc += x[n * 5 + f] * W[f * DIM + d];
    h[n * DIM + d] = fmaxf(acc, 0.f);
}

// ---------------- weight prep: split W into bf16 hi/lo, transposed [n][k] ----------------
__global__ __launch_bounds__(256) void prep_weights_kernel(const float* __restrict__ Wl, const float* __restrict__ Wr,
                                                           const float* __restrict__ c1W,
                                                           unsigned short* __restrict__ wt) {
    int idx = blockIdx.x * 256 + threadIdx.x;  // 8 * 16384
    int m = idx >> 14;
    int r = idx & 16383;
    int n = r >> 7, k = r & 127;
    int L = m >> 1, half = m & 1;
    const float* W;
    if (L < 3) W = (half ? Wr : Wl) + (size_t)L * 16384;
    else W = c1W + (size_t)half * 16384;
    float v = W[k * 128 + n];
    __hip_bfloat16 hb = __float2bfloat16(v);
    float rl = v - __bfloat162float(hb);
    __hip_bfloat16 lb = __float2bfloat16(rl);
    wt[(size_t)m * 32768 + n * 128 + k] = *reinterpret_cast<unsigned short*>(&hb);
    wt[(size_t)m * 32768 + 16384 + n * 128 + k] = *reinterpret_cast<unsigned short*>(&lb);
}

// ---------------- dual GEMM via split-bf16 MFMA, v2: wave = col-tiles (no W redundancy) ----------------
template <bool BF16OUT>
__global__ __launch_bounds__(256) void transform_mfma_kernel(const float* __restrict__ h,
                                                             const unsigned short* __restrict__ wtA,
                                                             const float* __restrict__ bA,
                                                             const unsigned short* __restrict__ wtB,
                                                             const float* __restrict__ bB,
                                                             void* __restrict__ outA_, void* __restrict__ outB_) {
    __shared__ __align__(16) char hhi[64 * 256];  // bf16 [64][128], XOR-swizzled 16B rows
    __shared__ __align__(16) char hlo[64 * 256];
    int t = threadIdx.x;
    int l = t & 63, w = t >> 6;
    int n0 = blockIdx.x * 64;
    for (int i = t; i < 64 * 32; i += 256) {
        int row = i >> 5, c4 = (i & 31) * 4;
        int n = n0 + row;
        float4 v = make_float4(0.f, 0.f, 0.f, 0.f);
        if (n < N_NODES) v = *(const float4*)&h[(size_t)n * DIM + c4];
        const float* pv = &v.x;
        unsigned short hi4[4], lo4[4];
#pragma unroll
        for (int q = 0; q < 4; q++) {
            __hip_bfloat16 hb = __float2bfloat16(pv[q]);
            float rl = pv[q] - __bfloat162float(hb);
            __hip_bfloat16 lb = __float2bfloat16(rl);
            hi4[q] = *reinterpret_cast<unsigned short*>(&hb);
            lo4[q] = *reinterpret_cast<unsigned short*>(&lb);
        }
        int addr = (row * 256 + c4 * 2) ^ ((row & 7) << 4);
        *(ushort4*)(hhi + addr) = make_ushort4(hi4[0], hi4[1], hi4[2], hi4[3]);
        *(ushort4*)(hlo + addr) = make_ushort4(lo4[0], lo4[1], lo4[2], lo4[3]);
    }
    __syncthreads();

    int lane_m = l & 15, lane_k8 = l >> 4;

#pragma unroll
    for (int mat = 0; mat < 2; mat++) {
        const short* wthi = (const short*)(mat ? wtB : wtA);
        const short* wtlo = wthi + 16384;
        const float* bias = mat ? bB : bA;
        // hoist all B fragments for this wave's 2 col-tiles into registers (16 loads in flight)
        short8 bh[2][4], bl_[2][4];
#pragma unroll
        for (int j = 0; j < 2; j++) {
            int nrow = (w * 2 + j) * 16 + lane_m;
#pragma unroll
            for (int ks = 0; ks < 4; ks++) {
                int ke = ks * 32 + lane_k8 * 8;
                bh[j][ks] = *(const short8*)(wthi + nrow * 128 + ke);
                bl_[j][ks] = *(const short8*)(wtlo + nrow * 128 + ke);
            }
        }
        f32x4 acc[4][2];
#pragma unroll
        for (int mt = 0; mt < 4; mt++)
#pragma unroll
            for (int j = 0; j < 2; j++) acc[mt][j] = (f32x4){0.f, 0.f, 0.f, 0.f};
#pragma unroll
        for (int ks = 0; ks < 4; ks++) {
            int kb = ks * 64 + lane_k8 * 16;
#pragma unroll
            for (int mt = 0; mt < 4; mt++) {
                int arow = mt * 16 + lane_m;
                int aswz = (arow & 7) << 4;
                short8 ahi = *(const short8*)(hhi + ((arow * 256 + kb) ^ aswz));
                short8 alo = *(const short8*)(hlo + ((arow * 256 + kb) ^ aswz));
#pragma unroll
                for (int j = 0; j < 2; j++) {
                    acc[mt][j] = __builtin_amdgcn_mfma_f32_16x16x32_bf16(ahi, bh[j][ks], acc[mt][j], 0, 0, 0);
                    acc[mt][j] = __builtin_amdgcn_mfma_f32_16x16x32_bf16(ahi, bl_[j][ks], acc[mt][j], 0, 0, 0);
                    acc[mt][j] = __builtin_amdgcn_mfma_f32_16x16x32_bf16(alo, bh[j][ks], acc[mt][j], 0, 0, 0);
                }
            }
        }
        void* outp = mat ? outB_ : outA_;
#pragma unroll
        for (int j = 0; j < 2; j++) {
            int col = (w * 2 + j) * 16 + lane_m;
            float bv = bias ? bias[col] : 0.f;
#pragma unroll
            for (int mt = 0; mt < 4; mt++) {
#pragma unroll
                for (int r = 0; r < 4; r++) {
                    int node = n0 + mt * 16 + lane_k8 * 4 + r;
                    if (node < N_NODES) {
                        float v = acc[mt][j][r] + bv;
                        if constexpr (BF16OUT) {
                            ((__hip_bfloat16*)outp)[(size_t)node * DIM + col] = __float2bfloat16(v);
                        } else {
                            ((float*)outp)[(size_t)node * DIM + col] = v;
                        }
                    }
                }
            }
        }
    }
}

// ---------------- GATv2 edge+aggregate: wave-per-node, float4 lanes, 4 edges/iter ----------------
__device__ __forceinline__ float edge_score(float4 v, float4 xrv, float4 attv) {
    float z, a;
    z = v.x + xrv.x; z = fmaxf(z, NEG * z); a = z * attv.x;
    z = v.y + xrv.y; z = fmaxf(z, NEG * z); a += z * attv.y;
    z = v.z + xrv.z; z = fmaxf(z, NEG * z); a += z * attv.z;
    z = v.w + xrv.w; z = fmaxf(z, NEG * z); a += z * attv.w;
    a += __shfl_xor(a, 1);
    a += __shfl_xor(a, 2);
    a += __shfl_xor(a, 4);
    return a;
}

__global__ __launch_bounds__(256) void gat_edge_kernel(const float* __restrict__ xl, const float* __restrict__ xr,
                                                       const float* __restrict__ att, const float* __restrict__ gbias,
                                                       const int* __restrict__ indptr, const int* __restrict__ csr_src,
                                                       float* __restrict__ h_out) {
    int n = blockIdx.x * 4 + (threadIdx.x >> 6);  // wave-per-node
    int l = threadIdx.x & 63;
    int half = l >> 5;
    int c0 = (l & 31) * 4;
    float4 xrv = *(const float4*)&xr[(size_t)n * DIM + c0];
    float4 attv = *(const float4*)&att[c0];
    int beg = indptr[n], end = indptr[n + 1];

    float m[2], den[2];
    float4 acc[2];
    {
        float4 v = *(const float4*)&xl[(size_t)n * DIM + c0];
        float a = edge_score(v, xrv, attv);
        if (half == 0) {
            m[0] = a; den[0] = 1.f; acc[0] = v;
        } else {
            m[0] = -3.4e38f; den[0] = 0.f; acc[0] = make_float4(0.f, 0.f, 0.f, 0.f);
        }
        m[1] = -3.4e38f; den[1] = 0.f; acc[1] = make_float4(0.f, 0.f, 0.f, 0.f);
    }

    for (int i = beg; i < end; i += 4) {
#pragma unroll
        for (int c = 0; c < 2; c++) {
            int idx = i + 2 * c + half;
            bool valid = idx < end;
            int s = valid ? csr_src[idx] : n;
            float4 v = *(const float4*)&xl[(size_t)s * DIM + c0];
            float a = edge_score(v, xrv, attv);
            if (!valid) a = -3.4e38f;
            float mn = fmaxf(m[c], a);
            float sc = __expf(m[c] - mn), p = __expf(a - mn);
            den[c] = den[c] * sc + p;
            acc[c].x = acc[c].x * sc + p * v.x;
            acc[c].y = acc[c].y * sc + p * v.y;
            acc[c].z = acc[c].z * sc + p * v.z;
            acc[c].w = acc[c].w * sc + p * v.w;
            m[c] = mn;
        }
    }
    {
        float mm = fmaxf(m[0], m[1]);
        float s0 = __expf(m[0] - mm), s1 = __expf(m[1] - mm);
        den[0] = den[0] * s0 + den[1] * s1;
        acc[0].x = acc[0].x * s0 + acc[1].x * s1;
        acc[0].y = acc[0].y * s0 + acc[1].y * s1;
        acc[0].z = acc[0].z * s0 + acc[1].z * s1;
        acc[0].w = acc[0].w * s0 + acc[1].w * s1;
        m[0] = mm;
    }
    {
        float mo = __shfl_xor(m[0], 32);
        float dno = __shfl_xor(den[0], 32);
        float4 ao;
        ao.x = __shfl_xor(acc[0].x, 32);
        ao.y = __shfl_xor(acc[0].y, 32);
        ao.z = __shfl_xor(acc[0].z, 32);
        ao.w = __shfl_xor(acc[0].w, 32);
        float mm = fmaxf(m[0], mo);
        float s0 = __expf(m[0] - mm), s1 = __expf(mo - mm);
        den[0] = den[0] * s0 + dno * s1;
        acc[0].x = acc[0].x * s0 + ao.x * s1;
        acc[0].y = acc[0].y * s0 + ao.y * s1;
        acc[0].z = acc[0].z * s0 + ao.z * s1;
        acc[0].w = acc[0].w * s0 + ao.w * s1;
    }
    if (half == 0) {
        float4 gb = *(const float4*)&gbias[c0];
        float inv = 1.f / (den[0] + 1e-16f);
        float4 o;
        o.x = acc[0].x * inv + gb.x;
        o.y = acc[0].y * inv + gb.y;
        o.z = acc[0].z * inv + gb.z;
        o.w = acc[0].w * inv + gb.w;
        o.x = (o.x > 0.f) ? o.x : __expf(o.x) - 1.f;
        o.y = (o.y > 0.f) ? o.y : __expf(o.y) - 1.f;
        o.z = (o.z > 0.f) ? o.z : __expf(o.z) - 1.f;
        o.w = (o.w > 0.f) ? o.w : __expf(o.w) - 1.f;
        *(float4*)&h_out[(size_t)n * DIM + c0] = o;
    }
}

// ---------------- edge MLP v4: async-staged gathers + bf16 MFMA layer2, 64-edge tiles ----------------
__global__ __launch_bounds__(256) void edge_mlp_kernel(const unsigned* __restrict__ g1u, const unsigned* __restrict__ g2u,
                                                       const float* __restrict__ x, const int* __restrict__ ei,
                                                       const float* __restrict__ W1tail,  // c1_W rows 256,257
                                                       const float* __restrict__ W2, const float* __restrict__ b2,
                                                       const float* __restrict__ W3, const float* __restrict__ b3,
                                                       float* __restrict__ out, int ntiles) {
    __shared__ __align__(16) char smO1[64 * 256];   // 64 edges x 128 bf16, XOR-swizzled 16B
    __shared__ __align__(16) char smW2T[64 * 256];  // W2^T: [n][k] bf16, XOR-swizzled 16B
    __shared__ float smCw[2][128];
    __shared__ float smPart[4][64];
    __shared__ int rowi[2][64], coli[2][64];
    __shared__ float sdt[2][64], sdi[2][64];
    int t = threadIdx.x;
    int l = t & 63, w = t >> 6;
    int s4 = t & 15;
    int ebase = t >> 4;  // slot p covers edge ebase + p*16

    for (int idx = t; idx < 128 * 64; idx += 256) {
        int k = idx >> 6, n = idx & 63;
        __hip_bfloat16 bv = __float2bfloat16(W2[idx]);
        unsigned short us = *reinterpret_cast<unsigned short*>(&bv);
        int addr = (n * 256 + k * 2) ^ ((n & 7) << 4);
        *(unsigned short*)(smW2T + addr) = us;
    }
    if (t < 128) {
        smCw[0][t] = W1tail[t];
        smCw[1][t] = W1tail[128 + t];
    }
    float b3v = b3[0];
    float b2v = b2[w * 16 + (l & 15)];
    float w3v = W3[w * 16 + (l & 15)];
    int koff = (l >> 4) * 16;

    const uint4* g1t = (const uint4*)g1u;
    const uint4* g2t = (const uint4*)g2u;

    uint4 u1[4], u2[4];
    int cur = 0;

    // prologue: indices + gathers for first tile
    int tile0 = blockIdx.x;
    if (tile0 < ntiles) {
        if (t < 64) {
            int ge = tile0 * 64 + t;
            int r = ei[ge], c = ei[N_EDGES + ge];
            rowi[0][t] = r; coli[0][t] = c;
            sdt[0][t] = fabsf(x[r * 5 + 4] - x[c * 5 + 4]);
            float dx = x[r * 5 + 1] - x[c * 5 + 1];
            float dy = x[r * 5 + 2] - x[c * 5 + 2];
            float dz = x[r * 5 + 3] - x[c * 5 + 3];
            sdi[0][t] = sqrtf(dx * dx + dy * dy + dz * dz);
        }
        __syncthreads();
#pragma unroll
        for (int p = 0; p < 4; p++) {
            int e = ebase + p * 16;
            u1[p] = g1t[(size_t)rowi[0][e] * 16 + s4];
            u2[p] = g2t[(size_t)coli[0][e] * 16 + s4];
        }
    }

    for (int tile = blockIdx.x; tile < ntiles; tile += gridDim.x) {
        int nxt = tile + gridDim.x;
        __syncthreads();  // prev MFMA/out done; smO1 free (also fences W2T prefill on iter 0)
        // store current tile's pre-gathered regs -> smO1 (bf16, swizzled)
#pragma unroll
        for (int p = 0; p < 4; p++) {
            int e = ebase + p * 16;
            float dtv = sdt[cur][e], div = sdi[cur][e];
            unsigned uo[4];
            const unsigned* a1 = &u1[p].x;
            const unsigned* a2 = &u2[p].x;
#pragma unroll
            for (int q = 0; q < 4; q++) {
                int d = s4 * 8 + q * 2;
                float lo = __uint_as_float(a1[q] << 16) + __uint_as_float(a2[q] << 16) + dtv * smCw[0][d] + div * smCw[1][d];
                float hi = __uint_as_float(a1[q] & 0xffff0000u) + __uint_as_float(a2[q] & 0xffff0000u) +
                           dtv * smCw[0][d + 1] + div * smCw[1][d + 1];
                lo = fmaxf(lo, 0.f); hi = fmaxf(hi, 0.f);
                __hip_bfloat16 blo = __float2bfloat16(lo), bhi = __float2bfloat16(hi);
                unsigned short ulo = *reinterpret_cast<unsigned short*>(&blo);
                unsigned short uhi = *reinterpret_cast<unsigned short*>(&bhi);
                uo[q] = (unsigned)ulo | ((unsigned)uhi << 16);
            }
            int addr = (e * 256 + s4 * 16) ^ ((e & 7) << 4);
            *(uint4*)(smO1 + addr) = *(uint4*)uo;
        }
        // next tile's indices
        if (nxt < ntiles && t < 64) {
            int b = cur ^ 1;
            int ge = nxt * 64 + t;
            int r = ei[ge], c = ei[N_EDGES + ge];
            rowi[b][t] = r; coli[b][t] = c;
            sdt[b][t] = fabsf(x[r * 5 + 4] - x[c * 5 + 4]);
            float dx = x[r * 5 + 1] - x[c * 5 + 1];
            float dy = x[r * 5 + 2] - x[c * 5 + 2];
            float dz = x[r * 5 + 3] - x[c * 5 + 3];
            sdi[b][t] = sqrtf(dx * dx + dy * dy + dz * dz);
        }
        __syncthreads();  // smO1 ready; next-tile indices published
        // issue next tile's gathers (latency hides under MFMA below)
        if (nxt < ntiles) {
            int b = cur ^ 1;
#pragma unroll
            for (int p = 0; p < 4; p++) {
                int e = ebase + p * 16;
                u1[p] = g1t[(size_t)rowi[b][e] * 16 + s4];
                u2[p] = g2t[(size_t)coli[b][e] * 16 + s4];
            }
        }
        // layer 2 via MFMA
        f32x4 acc[4];
#pragma unroll
        for (int mt = 0; mt < 4; mt++) acc[mt] = (f32x4){0.f, 0.f, 0.f, 0.f};
        int nrow = w * 16 + (l & 15);
#pragma unroll
        for (int ks = 0; ks < 4; ks++) {
            short8 bfrag = *(const short8*)(smW2T + ((nrow * 256 + koff + ks * 64) ^ ((nrow & 7) << 4)));
#pragma unroll
            for (int mt = 0; mt < 4; mt++) {
                int mrow = mt * 16 + (l & 15);
                short8 afrag = *(const short8*)(smO1 + ((mrow * 256 + koff + ks * 64) ^ ((mrow & 7) << 4)));
                acc[mt] = __builtin_amdgcn_mfma_f32_16x16x32_bf16(afrag, bfrag, acc[mt], 0, 0, 0);
            }
        }
        // layer 3
        float p[4][4];
#pragma unroll
        for (int mt = 0; mt < 4; mt++)
#pragma unroll
            for (int r = 0; r < 4; r++) p[mt][r] = fmaxf(acc[mt][r] + b2v, 0.f) * w3v;
#pragma unroll
        for (int off = 8; off >= 1; off >>= 1)
#pragma unroll
            for (int mt = 0; mt < 4; mt++)
#pragma unroll
                for (int r = 0; r < 4; r++) p[mt][r] += __shfl_xor(p[mt][r], off);
        if ((l & 15) == 0) {
            int g = l >> 4;
#pragma unroll
            for (int mt = 0; mt < 4; mt++)
#pragma unroll
                for (int r = 0; r < 4; r++) smPart[w][mt * 16 + g * 4 + r] = p[mt][r];
        }
        __syncthreads();
        if (t < 64) out[tile * 64 + t] = smPart[0][t] + smPart[1][t] + smPart[2][t] + smPart[3][t] + b3v;
        cur ^= 1;
    }
}

extern "C" void kernel_launch(void* const* d_in, const int* in_sizes, int n_in,
                              void* d_out, int out_size, void* d_ws, size_t ws_size,
                              hipStream_t stream) {
    const float* x = (const float*)d_in[0];
    const int* ei = (const int*)d_in[1];
    const float* enc_W = (const float*)d_in[2];
    const float* enc_b = (const float*)d_in[3];
    const float* Wl = (const float*)d_in[4];
    const float* bl = (const float*)d_in[5];
    const float* Wr = (const float*)d_in[6];
    const float* br = (const float*)d_in[7];
    const float* att = (const float*)d_in[8];
    const float* gbias = (const float*)d_in[9];
    const float* c1_W = (const float*)d_in[10];
    const float* c1_b = (const float*)d_in[11];
    const float* c2_W = (const float*)d_in[12];
    const float* c2_b = (const float*)d_in[13];
    const float* c3_W = (const float*)d_in[14];
    const float* c3_b = (const float*)d_in[15];
    float* out = (float*)d_out;

    float* h = (float*)d_ws;
    float* xl = h + (size_t)N_NODES * DIM;
    float* xr = xl + (size_t)N_NODES * DIM;
    int* csr_src = (int*)(xr + (size_t)N_NODES * DIM);
    int* indptr = csr_src + N_EDGES;
    int* counts = indptr + (N_NODES + 1);
    int* bsum = counts + N_NODES;
    int* boff = bsum + 256;
    uintptr_t wp = (uintptr_t)(boff + 256);
    wp = (wp + 15) & ~(uintptr_t)15;
    unsigned short* wt = (unsigned short*)wp;  // 8 matrices x {hi,lo} x 16384 bf16 = 512 KB

    const int* srcp = ei;
    const int* dstp = ei + N_EDGES;
    const int NB = (N_NODES + 255) / 256;  // 196
    const int TGRID = (N_NODES + 63) / 64;  // 782

    // weight prep (transpose + hi/lo split)
    prep_weights_kernel<<<8 * 16384 / 256, 256, 0, stream>>>(Wl, Wr, c1_W, wt);

    // CSR build
    zero_kernel<<<(N_NODES + 255) / 256, 256, 0, stream>>>(counts, N_NODES);
    hist_kernel<<<N_EDGES / 256, 256, 0, stream>>>(dstp, counts);
    scan1_kernel<<<NB, 256, 0, stream>>>(counts, indptr, bsum, N_NODES);
    scan2_kernel<<<1, 256, 0, stream>>>(bsum, boff, indptr, NB);
    scan3_kernel<<<NB, 256, 0, stream>>>(indptr, boff, N_NODES);
    zero_kernel<<<(N_NODES + 255) / 256, 256, 0, stream>>>(counts, N_NODES);
    place_kernel<<<N_EDGES / 256, 256, 0, stream>>>(srcp, dstp, indptr, counts, csr_src);

    // encoder
    encoder_kernel<<<(N_NODES * DIM) / 256, 256, 0, stream>>>(x, enc_W, enc_b, h);

    // GAT layers
    for (int i = 0; i < NLAYER; i++) {
        transform_mfma_kernel<false><<<TGRID, 256, 0, stream>>>(
            h, wt + (size_t)(i * 2) * 32768, bl + (size_t)i * DIM,
            wt + (size_t)(i * 2 + 1) * 32768, br + (size_t)i * DIM, xl, xr);
        gat_edge_kernel<<<N_NODES / 4, 256, 0, stream>>>(xl, xr, att + (size_t)i * DIM,
                                                         gbias + (size_t)i * DIM, indptr, csr_src, h);
    }

    // classifier layer-1 node-level split: g1 = h@W1a + b1, g2 = h@W1b (bf16 storage; reuse xl/xr)
    transform_mfma_kernel<true><<<TGRID, 256, 0, stream>>>(
        h, wt + (size_t)6 * 32768, c1_b, wt + (size_t)7 * 32768, nullptr, xl, xr);

    // fused edge MLP (64-edge tiles, MFMA layer2, async-staged gathers)
    edge_mlp_kernel<<<1024, 256, 0, stream>>>((const unsigned*)xl, (const unsigned*)xr, x, ei,
                                              c1_W + 256 * DIM, c2_W, c2_b, c3_W, c3_b, out, N_EDGES / 64);
}

// Round 8
// 558.101 us; speedup vs baseline: 4.4431x; 1.0684x over previous
//
#include <hip/hip_runtime.h>
#include <hip/hip_bf16.h>

#define N_NODES 50000
#define N_EDGES 800000
#define DIM 128
#define NLAYER 3
#define NEG 0.2f

typedef __attribute__((ext_vector_type(8))) short short8;
typedef __attribute__((ext_vector_type(4))) float f32x4;

// ---------------- utility ----------------
__global__ __launch_bounds__(256) void zero_kernel(int* p, int n) {
    int i = blockIdx.x * 256 + threadIdx.x;
    if (i < n) p[i] = 0;
}

// ---------------- CSR build ----------------
__global__ __launch_bounds__(256) void hist_kernel(const int* __restrict__ dst, int* __restrict__ counts) {
    int e = blockIdx.x * 256 + threadIdx.x;
    if (e < N_EDGES) atomicAdd(&counts[dst[e]], 1);
}

__global__ __launch_bounds__(256) void scan1_kernel(const int* __restrict__ counts, int* __restrict__ indptr,
                                                    int* __restrict__ bsum, int n) {
    __shared__ int buf[256];
    int t = threadIdx.x;
    int i = blockIdx.x * 256 + t;
    int v = (i < n) ? counts[i] : 0;
    buf[t] = v;
    __syncthreads();
    for (int off = 1; off < 256; off <<= 1) {
        int add = (t >= off) ? buf[t - off] : 0;
        __syncthreads();
        buf[t] += add;
        __syncthreads();
    }
    if (i < n) indptr[i + 1] = buf[t];
    if (t == 255) bsum[blockIdx.x] = buf[255];
}

__global__ __launch_bounds__(256) void scan2_kernel(int* __restrict__ bsum, int* __restrict__ boff,
                                                    int* __restrict__ indptr, int nb) {
    __shared__ int buf[256];
    int t = threadIdx.x;
    int v = (t < nb) ? bsum[t] : 0;
    buf[t] = v;
    __syncthreads();
    for (int off = 1; off < 256; off <<= 1) {
        int add = (t >= off) ? buf[t - off] : 0;
        __syncthreads();
        buf[t] += add;
        __syncthreads();
    }
    if (t < nb) boff[t] = buf[t] - v;  // exclusive
    if (t == 0) indptr[0] = 0;
}

__global__ __launch_bounds__(256) void scan3_kernel(int* __restrict__ indptr, const int* __restrict__ boff, int n) {
    int i = blockIdx.x * 256 + threadIdx.x;
    if (i < n) indptr[i + 1] += boff[i >> 8];
}

__global__ __launch_bounds__(256) void place_kernel(const int* __restrict__ srcp, const int* __restrict__ dstp,
                                                    const int* __restrict__ indptr, int* __restrict__ cursor,
                                                    int* __restrict__ csr_src, int* __restrict__ csr_dst,
                                                    int* __restrict__ csr_eid) {
    int e = blockIdx.x * 256 + threadIdx.x;
    if (e < N_EDGES) {
        int dn = dstp[e];
        int pos = indptr[dn] + atomicAdd(&cursor[dn], 1);
        csr_src[pos] = srcp[e];
        csr_dst[pos] = dn;
        csr_eid[pos] = e;
    }
}

// ---------------- encoder: h = relu(x @ enc_W + enc_b) ----------------
__global__ __launch_bounds__(256) void encoder_kernel(const float* __restrict__ x, const float* __restrict__ W,
                                                      const float* __restrict__ b, float* __restrict__ h) {
    int gid = blockIdx.x * 256 + threadIdx.x;
    int n = gid >> 7, d = gid & 127;
    if (n >= N_NODES) return;
    float acc = b[d];
#pragma unroll
    for (int f = 0; f < 5; f++) acc += x[n * 5 + f] * W[f * DIM + d];
    h[n * DIM + d] = fmaxf(acc, 0.f);
}

// ---------------- weight prep: split W into bf16 hi/lo, transposed [n][k] ----------------
__global__ __launch_bounds__(256) void prep_weights_kernel(const float* __restrict__ Wl, const float* __restrict__ Wr,
                                                           const float* __restrict__ c1W,
                                                           unsigned short* __restrict__ wt) {
    int idx = blockIdx.x * 256 + threadIdx.x;  // 8 * 16384
    int m = idx >> 14;
    int r = idx & 16383;
    int n = r >> 7, k = r & 127;
    int L = m >> 1, half = m & 1;
    const float* W;
    if (L < 3) W = (half ? Wr : Wl) + (size_t)L * 16384;
    else W = c1W + (size_t)half * 16384;
    float v = W[k * 128 + n];
    __hip_bfloat16 hb = __float2bfloat16(v);
    float rl = v - __bfloat162float(hb);
    __hip_bfloat16 lb = __float2bfloat16(rl);
    wt[(size_t)m * 32768 + n * 128 + k] = *reinterpret_cast<unsigned short*>(&hb);
    wt[(size_t)m * 32768 + 16384 + n * 128 + k] = *reinterpret_cast<unsigned short*>(&lb);
}

// ---------------- dual GEMM via split-bf16 MFMA, v2: wave = col-tiles (no W redundancy) ----------------
template <bool BF16OUT>
__global__ __launch_bounds__(256) void transform_mfma_kernel(const float* __restrict__ h,
                                                             const unsigned short* __restrict__ wtA,
                                                             const float* __restrict__ bA,
                                                             const unsigned short* __restrict__ wtB,
                                                             const float* __restrict__ bB,
                                                             void* __restrict__ outA_, void* __restrict__ outB_) {
    __shared__ __align__(16) char hhi[64 * 256];  // bf16 [64][128], XOR-swizzled 16B rows
    __shared__ __align__(16) char hlo[64 * 256];
    int t = threadIdx.x;
    int l = t & 63, w = t >> 6;
    int n0 = blockIdx.x * 64;
    for (int i = t; i < 64 * 32; i += 256) {
        int row = i >> 5, c4 = (i & 31) * 4;
        int n = n0 + row;
        float4 v = make_float4(0.f, 0.f, 0.f, 0.f);
        if (n < N_NODES) v = *(const float4*)&h[(size_t)n * DIM + c4];
        const float* pv = &v.x;
        unsigned short hi4[4], lo4[4];
#pragma unroll
        for (int q = 0; q < 4; q++) {
            __hip_bfloat16 hb = __float2bfloat16(pv[q]);
            float rl = pv[q] - __bfloat162float(hb);
            __hip_bfloat16 lb = __float2bfloat16(rl);
            hi4[q] = *reinterpret_cast<unsigned short*>(&hb);
            lo4[q] = *reinterpret_cast<unsigned short*>(&lb);
        }
        int addr = (row * 256 + c4 * 2) ^ ((row & 7) << 4);
        *(ushort4*)(hhi + addr) = make_ushort4(hi4[0], hi4[1], hi4[2], hi4[3]);
        *(ushort4*)(hlo + addr) = make_ushort4(lo4[0], lo4[1], lo4[2], lo4[3]);
    }
    __syncthreads();

    int lane_m = l & 15, lane_k8 = l >> 4;

#pragma unroll
    for (int mat = 0; mat < 2; mat++) {
        const short* wthi = (const short*)(mat ? wtB : wtA);
        const short* wtlo = wthi + 16384;
        const float* bias = mat ? bB : bA;
        short8 bh[2][4], bl_[2][4];
#pragma unroll
        for (int j = 0; j < 2; j++) {
            int nrow = (w * 2 + j) * 16 + lane_m;
#pragma unroll
            for (int ks = 0; ks < 4; ks++) {
                int ke = ks * 32 + lane_k8 * 8;
                bh[j][ks] = *(const short8*)(wthi + nrow * 128 + ke);
                bl_[j][ks] = *(const short8*)(wtlo + nrow * 128 + ke);
            }
        }
        f32x4 acc[4][2];
#pragma unroll
        for (int mt = 0; mt < 4; mt++)
#pragma unroll
            for (int j = 0; j < 2; j++) acc[mt][j] = (f32x4){0.f, 0.f, 0.f, 0.f};
#pragma unroll
        for (int ks = 0; ks < 4; ks++) {
            int kb = ks * 64 + lane_k8 * 16;
#pragma unroll
            for (int mt = 0; mt < 4; mt++) {
                int arow = mt * 16 + lane_m;
                int aswz = (arow & 7) << 4;
                short8 ahi = *(const short8*)(hhi + ((arow * 256 + kb) ^ aswz));
                short8 alo = *(const short8*)(hlo + ((arow * 256 + kb) ^ aswz));
#pragma unroll
                for (int j = 0; j < 2; j++) {
                    acc[mt][j] = __builtin_amdgcn_mfma_f32_16x16x32_bf16(ahi, bh[j][ks], acc[mt][j], 0, 0, 0);
                    acc[mt][j] = __builtin_amdgcn_mfma_f32_16x16x32_bf16(ahi, bl_[j][ks], acc[mt][j], 0, 0, 0);
                    acc[mt][j] = __builtin_amdgcn_mfma_f32_16x16x32_bf16(alo, bh[j][ks], acc[mt][j], 0, 0, 0);
                }
            }
        }
        void* outp = mat ? outB_ : outA_;
#pragma unroll
        for (int j = 0; j < 2; j++) {
            int col = (w * 2 + j) * 16 + lane_m;
            float bv = bias ? bias[col] : 0.f;
#pragma unroll
            for (int mt = 0; mt < 4; mt++) {
#pragma unroll
                for (int r = 0; r < 4; r++) {
                    int node = n0 + mt * 16 + lane_k8 * 4 + r;
                    if (node < N_NODES) {
                        float v = acc[mt][j][r] + bv;
                        if constexpr (BF16OUT) {
                            ((__hip_bfloat16*)outp)[(size_t)node * DIM + col] = __float2bfloat16(v);
                        } else {
                            ((float*)outp)[(size_t)node * DIM + col] = v;
                        }
                    }
                }
            }
        }
    }
}

// ---------------- GATv2 edge+aggregate v4: wave-per-node, 8 edges/iter, 4 chains ----------------
__global__ __launch_bounds__(256) void gat_edge_kernel(const float* __restrict__ xl, const float* __restrict__ xr,
                                                       const float* __restrict__ att, const float* __restrict__ gbias,
                                                       const int* __restrict__ indptr, const int* __restrict__ csr_src,
                                                       float* __restrict__ h_out) {
    int n = blockIdx.x * 4 + (threadIdx.x >> 6);  // wave-per-node
    int l = threadIdx.x & 63;
    int half = l >> 5;
    int c0 = (l & 31) * 4;
    float4 xrv = *(const float4*)&xr[(size_t)n * DIM + c0];
    float4 attv = *(const float4*)&att[c0];
    int beg = indptr[n], end = indptr[n + 1];

    float m[4], den[4];
    float4 acc[4];
    // self-loop seeds chain 0 of half 0
    {
        float4 v = *(const float4*)&xl[(size_t)n * DIM + c0];
        float z, a;
        z = v.x + xrv.x; z = fmaxf(z, NEG * z); a = z * attv.x;
        z = v.y + xrv.y; z = fmaxf(z, NEG * z); a += z * attv.y;
        z = v.z + xrv.z; z = fmaxf(z, NEG * z); a += z * attv.z;
        z = v.w + xrv.w; z = fmaxf(z, NEG * z); a += z * attv.w;
        a += __shfl_xor(a, 1);
        a += __shfl_xor(a, 2);
        a += __shfl_xor(a, 4);
        if (half == 0) {
            m[0] = a; den[0] = 1.f; acc[0] = v;
        } else {
            m[0] = -3.4e38f; den[0] = 0.f; acc[0] = make_float4(0.f, 0.f, 0.f, 0.f);
        }
#pragma unroll
        for (int c = 1; c < 4; c++) { m[c] = -3.4e38f; den[c] = 0.f; acc[c] = make_float4(0.f, 0.f, 0.f, 0.f); }
    }

    for (int i = beg; i < end; i += 8) {
        int s[4];
        bool val[4];
        float4 v[4];
        float a[4];
#pragma unroll
        for (int c = 0; c < 4; c++) {
            int idx = i + 2 * c + half;
            val[c] = idx < end;
            s[c] = val[c] ? csr_src[idx] : n;
        }
#pragma unroll
        for (int c = 0; c < 4; c++) v[c] = *(const float4*)&xl[(size_t)s[c] * DIM + c0];
#pragma unroll
        for (int c = 0; c < 4; c++) {
            float z, aa;
            z = v[c].x + xrv.x; z = fmaxf(z, NEG * z); aa = z * attv.x;
            z = v[c].y + xrv.y; z = fmaxf(z, NEG * z); aa += z * attv.y;
            z = v[c].z + xrv.z; z = fmaxf(z, NEG * z); aa += z * attv.z;
            z = v[c].w + xrv.w; z = fmaxf(z, NEG * z); aa += z * attv.w;
            a[c] = aa;
        }
#pragma unroll
        for (int off = 1; off <= 4; off <<= 1)
#pragma unroll
            for (int c = 0; c < 4; c++) a[c] += __shfl_xor(a[c], off);
#pragma unroll
        for (int c = 0; c < 4; c++) {
            if (!val[c]) a[c] = -3.4e38f;
            float mn = fmaxf(m[c], a[c]);
            float sc = __expf(m[c] - mn), p = __expf(a[c] - mn);
            den[c] = den[c] * sc + p;
            acc[c].x = acc[c].x * sc + p * v[c].x;
            acc[c].y = acc[c].y * sc + p * v[c].y;
            acc[c].z = acc[c].z * sc + p * v[c].z;
            acc[c].w = acc[c].w * sc + p * v[c].w;
            m[c] = mn;
        }
    }
    // merge 4 chains into chain 0 (lane-local)
#pragma unroll
    for (int c = 1; c < 4; c++) {
        float mm = fmaxf(m[0], m[c]);
        float s0 = __expf(m[0] - mm), s1 = __expf(m[c] - mm);
        den[0] = den[0] * s0 + den[c] * s1;
        acc[0].x = acc[0].x * s0 + acc[c].x * s1;
        acc[0].y = acc[0].y * s0 + acc[c].y * s1;
        acc[0].z = acc[0].z * s0 + acc[c].z * s1;
        acc[0].w = acc[0].w * s0 + acc[c].w * s1;
        m[0] = mm;
    }
    // merge across halves (lane l <-> l^32)
    {
        float mo = __shfl_xor(m[0], 32);
        float dno = __shfl_xor(den[0], 32);
        float4 ao;
        ao.x = __shfl_xor(acc[0].x, 32);
        ao.y = __shfl_xor(acc[0].y, 32);
        ao.z = __shfl_xor(acc[0].z, 32);
        ao.w = __shfl_xor(acc[0].w, 32);
        float mm = fmaxf(m[0], mo);
        float s0 = __expf(m[0] - mm), s1 = __expf(mo - mm);
        den[0] = den[0] * s0 + dno * s1;
        acc[0].x = acc[0].x * s0 + ao.x * s1;
        acc[0].y = acc[0].y * s0 + ao.y * s1;
        acc[0].z = acc[0].z * s0 + ao.z * s1;
        acc[0].w = acc[0].w * s0 + ao.w * s1;
    }
    if (half == 0) {
        float4 gb = *(const float4*)&gbias[c0];
        float inv = 1.f / (den[0] + 1e-16f);
        float4 o;
        o.x = acc[0].x * inv + gb.x;
        o.y = acc[0].y * inv + gb.y;
        o.z = acc[0].z * inv + gb.z;
        o.w = acc[0].w * inv + gb.w;
        o.x = (o.x > 0.f) ? o.x : __expf(o.x) - 1.f;
        o.y = (o.y > 0.f) ? o.y : __expf(o.y) - 1.f;
        o.z = (o.z > 0.f) ? o.z : __expf(o.z) - 1.f;
        o.w = (o.w > 0.f) ? o.w : __expf(o.w) - 1.f;
        *(float4*)&h_out[(size_t)n * DIM + c0] = o;
    }
}

// ---------------- edge MLP v5: CSR-ordered (dst-local g2), interleaved gathers, MFMA layer2 ----------------
__global__ __launch_bounds__(256) void edge_mlp_kernel(const unsigned* __restrict__ g1u, const unsigned* __restrict__ g2u,
                                                       const float* __restrict__ x,
                                                       const int* __restrict__ csr_src, const int* __restrict__ csr_dst,
                                                       const int* __restrict__ csr_eid,
                                                       const float* __restrict__ W1tail,  // c1_W rows 256,257
                                                       const float* __restrict__ W2, const float* __restrict__ b2,
                                                       const float* __restrict__ W3, const float* __restrict__ b3,
                                                       float* __restrict__ out, int ntiles) {
    __shared__ __align__(16) char smO1[64 * 256];   // 64 edges x 128 bf16, XOR-swizzled 16B
    __shared__ __align__(16) char smW2T[64 * 256];  // W2^T: [n][k] bf16, XOR-swizzled 16B
    __shared__ float smCw[2][128];
    __shared__ float smPart[4][64];
    __shared__ int rowi[64], coli[64], seid[64];
    __shared__ float sdt[64], sdi[64];
    int t = threadIdx.x;
    int l = t & 63, w = t >> 6;

    for (int idx = t; idx < 128 * 64; idx += 256) {
        int k = idx >> 6, n = idx & 63;
        __hip_bfloat16 bv = __float2bfloat16(W2[idx]);
        unsigned short us = *reinterpret_cast<unsigned short*>(&bv);
        int addr = (n * 256 + k * 2) ^ ((n & 7) << 4);
        *(unsigned short*)(smW2T + addr) = us;
    }
    if (t < 128) {
        smCw[0][t] = W1tail[t];
        smCw[1][t] = W1tail[128 + t];
    }
    float b3v = b3[0];
    float b2v = b2[w * 16 + (l & 15)];
    float w3v = W3[w * 16 + (l & 15)];
    int koff = (l >> 4) * 16;

    const uint4* g1t = (const uint4*)g1u;
    const uint4* g2t = (const uint4*)g2u;

    for (int tile = blockIdx.x; tile < ntiles; tile += gridDim.x) {
        int p0 = tile * 64;
        __syncthreads();  // prev tile fully consumed (also first-iter LDS prefill fence)
        if (t < 64) {
            int p = p0 + t;
            int r = csr_src[p], c = csr_dst[p];
            rowi[t] = r; coli[t] = c; seid[t] = csr_eid[p];
            sdt[t] = fabsf(x[r * 5 + 4] - x[c * 5 + 4]);
            float dx = x[r * 5 + 1] - x[c * 5 + 1];
            float dy = x[r * 5 + 2] - x[c * 5 + 2];
            float dz = x[r * 5 + 3] - x[c * 5 + 3];
            sdi[t] = sqrtf(dx * dx + dy * dy + dz * dz);
        }
        __syncthreads();
        // build o1: each thread one 16B slot (8 dims) of one edge; gathers interleaved
        for (int idx = t; idx < 64 * 16; idx += 256) {
            int e = idx >> 4, s4 = idx & 15;
            uint4 u1 = g1t[(size_t)rowi[e] * 16 + s4];
            uint4 u2 = g2t[(size_t)coli[e] * 16 + s4];
            float dtv = sdt[e], div = sdi[e];
            unsigned uo[4];
            const unsigned* a1 = &u1.x;
            const unsigned* a2 = &u2.x;
#pragma unroll
            for (int q = 0; q < 4; q++) {
                int d = s4 * 8 + q * 2;
                float lo = __uint_as_float(a1[q] << 16) + __uint_as_float(a2[q] << 16) + dtv * smCw[0][d] + div * smCw[1][d];
                float hi = __uint_as_float(a1[q] & 0xffff0000u) + __uint_as_float(a2[q] & 0xffff0000u) +
                           dtv * smCw[0][d + 1] + div * smCw[1][d + 1];
                lo = fmaxf(lo, 0.f); hi = fmaxf(hi, 0.f);
                __hip_bfloat16 blo = __float2bfloat16(lo), bhi = __float2bfloat16(hi);
                unsigned short ulo = *reinterpret_cast<unsigned short*>(&blo);
                unsigned short uhi = *reinterpret_cast<unsigned short*>(&bhi);
                uo[q] = (unsigned)ulo | ((unsigned)uhi << 16);
            }
            int addr = (e * 256 + s4 * 16) ^ ((e & 7) << 4);
            *(uint4*)(smO1 + addr) = *(uint4*)uo;
        }
        __syncthreads();
        // layer 2 via MFMA
        f32x4 acc[4];
#pragma unroll
        for (int mt = 0; mt < 4; mt++) acc[mt] = (f32x4){0.f, 0.f, 0.f, 0.f};
        int nrow = w * 16 + (l & 15);
#pragma unroll
        for (int ks = 0; ks < 4; ks++) {
            short8 bfrag = *(const short8*)(smW2T + ((nrow * 256 + koff + ks * 64) ^ ((nrow & 7) << 4)));
#pragma unroll
            for (int mt = 0; mt < 4; mt++) {
                int mrow = mt * 16 + (l & 15);
                short8 afrag = *(const short8*)(smO1 + ((mrow * 256 + koff + ks * 64) ^ ((mrow & 7) << 4)));
                acc[mt] = __builtin_amdgcn_mfma_f32_16x16x32_bf16(afrag, bfrag, acc[mt], 0, 0, 0);
            }
        }
        // layer 3
        float p[4][4];
#pragma unroll
        for (int mt = 0; mt < 4; mt++)
#pragma unroll
            for (int r = 0; r < 4; r++) p[mt][r] = fmaxf(acc[mt][r] + b2v, 0.f) * w3v;
#pragma unroll
        for (int off = 8; off >= 1; off >>= 1)
#pragma unroll
            for (int mt = 0; mt < 4; mt++)
#pragma unroll
                for (int r = 0; r < 4; r++) p[mt][r] += __shfl_xor(p[mt][r], off);
        if ((l & 15) == 0) {
            int g = l >> 4;
#pragma unroll
            for (int mt = 0; mt < 4; mt++)
#pragma unroll
                for (int r = 0; r < 4; r++) smPart[w][mt * 16 + g * 4 + r] = p[mt][r];
        }
        __syncthreads();
        if (t < 64) out[seid[t]] = smPart[0][t] + smPart[1][t] + smPart[2][t] + smPart[3][t] + b3v;
    }
}

extern "C" void kernel_launch(void* const* d_in, const int* in_sizes, int n_in,
                              void* d_out, int out_size, void* d_ws, size_t ws_size,
                              hipStream_t stream) {
    const float* x = (const float*)d_in[0];
    const int* ei = (const int*)d_in[1];
    const float* enc_W = (const float*)d_in[2];
    const float* enc_b = (const float*)d_in[3];
    const float* Wl = (const float*)d_in[4];
    const float* bl = (const float*)d_in[5];
    const float* Wr = (const float*)d_in[6];
    const float* br = (const float*)d_in[7];
    const float* att = (const float*)d_in[8];
    const float* gbias = (const float*)d_in[9];
    const float* c1_W = (const float*)d_in[10];
    const float* c1_b = (const float*)d_in[11];
    const float* c2_W = (const float*)d_in[12];
    const float* c2_b = (const float*)d_in[13];
    const float* c3_W = (const float*)d_in[14];
    const float* c3_b = (const float*)d_in[15];
    float* out = (float*)d_out;

    float* h = (float*)d_ws;
    float* xl = h + (size_t)N_NODES * DIM;
    float* xr = xl + (size_t)N_NODES * DIM;
    int* csr_src = (int*)(xr + (size_t)N_NODES * DIM);
    int* csr_dst = csr_src + N_EDGES;
    int* csr_eid = csr_dst + N_EDGES;
    int* indptr = csr_eid + N_EDGES;
    int* counts = indptr + (N_NODES + 1);
    int* bsum = counts + N_NODES;
    int* boff = bsum + 256;
    uintptr_t wp = (uintptr_t)(boff + 256);
    wp = (wp + 15) & ~(uintptr_t)15;
    unsigned short* wt = (unsigned short*)wp;  // 8 matrices x {hi,lo} x 16384 bf16 = 512 KB

    const int* srcp = ei;
    const int* dstp = ei + N_EDGES;
    const int NB = (N_NODES + 255) / 256;  // 196
    const int TGRID = (N_NODES + 63) / 64;  // 782

    // weight prep (transpose + hi/lo split)
    prep_weights_kernel<<<8 * 16384 / 256, 256, 0, stream>>>(Wl, Wr, c1_W, wt);

    // CSR build
    zero_kernel<<<(N_NODES + 255) / 256, 256, 0, stream>>>(counts, N_NODES);
    hist_kernel<<<N_EDGES / 256, 256, 0, stream>>>(dstp, counts);
    scan1_kernel<<<NB, 256, 0, stream>>>(counts, indptr, bsum, N_NODES);
    scan2_kernel<<<1, 256, 0, stream>>>(bsum, boff, indptr, NB);
    scan3_kernel<<<NB, 256, 0, stream>>>(indptr, boff, N_NODES);
    zero_kernel<<<(N_NODES + 255) / 256, 256, 0, stream>>>(counts, N_NODES);
    place_kernel<<<N_EDGES / 256, 256, 0, stream>>>(srcp, dstp, indptr, counts, csr_src, csr_dst, csr_eid);

    // encoder
    encoder_kernel<<<(N_NODES * DIM) / 256, 256, 0, stream>>>(x, enc_W, enc_b, h);

    // GAT layers
    for (int i = 0; i < NLAYER; i++) {
        transform_mfma_kernel<false><<<TGRID, 256, 0, stream>>>(
            h, wt + (size_t)(i * 2) * 32768, bl + (size_t)i * DIM,
            wt + (size_t)(i * 2 + 1) * 32768, br + (size_t)i * DIM, xl, xr);
        gat_edge_kernel<<<N_NODES / 4, 256, 0, stream>>>(xl, xr, att + (size_t)i * DIM,
                                                         gbias + (size_t)i * DIM, indptr, csr_src, h);
    }

    // classifier layer-1 node-level split: g1 = h@W1a + b1, g2 = h@W1b (bf16 storage; reuse xl/xr)
    transform_mfma_kernel<true><<<TGRID, 256, 0, stream>>>(
        h, wt + (size_t)6 * 32768, c1_b, wt + (size_t)7 * 32768, nullptr, xl, xr);

    // fused edge MLP (CSR-ordered, 64-edge tiles, MFMA layer2)
    edge_mlp_kernel<<<1024, 256, 0, stream>>>((const unsigned*)xl, (const unsigned*)xr, x,
                                              csr_src, csr_dst, csr_eid, c1_W + 256 * DIM,
                                              c2_W, c2_b, c3_W, c3_b, out, N_EDGES / 64);
}